// Round 5
// baseline (836.626 us; speedup 1.0000x reference)
//
#include <hip/hip_runtime.h>
#include <hip/hip_bf16.h>

#define HEADS 4

// ---------------- edge dtype detection (int32 vs int64 layout) ----------------
// If edge_index is int64, every odd 32-bit word (high half) is 0.
__global__ void detect_kernel(const int* __restrict__ eidx, int* __restrict__ flag) {
    if (blockIdx.x == 0 && threadIdx.x == 0) {
        int orv = 0;
        for (int i = 0; i < 256; ++i) orv |= eidx[2 * i + 1];
        *flag = (orv == 0) ? 1 : 0;  // 1 = int64 layout
    }
}

__device__ __forceinline__ int edge_elem(const int* e, size_t idx, int is64) {
    return is64 ? e[2 * idx] : e[idx];
}

// ---------------- CSR build ----------------
__global__ void deg_kernel(const int* __restrict__ eidx, const int* __restrict__ flag,
                           int* __restrict__ deg, int E, int N) {
    int e = blockIdx.x * blockDim.x + threadIdx.x;
    if (e < E) {
        int is64 = *flag;
        int d = edge_elem(eidx, (size_t)E + e, is64);
        if ((unsigned)d < (unsigned)N) atomicAdd(&deg[d], 1);
    }
}

__global__ void scan_kernel(const int* __restrict__ deg, int* __restrict__ rowptr,
                            int* __restrict__ cursor, int n) {
    __shared__ int buf[1024];
    __shared__ int carry;
    int tid = threadIdx.x;
    if (tid == 0) carry = 0;
    __syncthreads();
    for (int base = 0; base < n; base += 1024) {
        int i = base + tid;
        int v = (i < n) ? deg[i] : 0;
        buf[tid] = v;
        __syncthreads();
        for (int off = 1; off < 1024; off <<= 1) {
            int t = (tid >= off) ? buf[tid - off] : 0;
            __syncthreads();
            buf[tid] += t;
            __syncthreads();
        }
        int incl = buf[tid];
        int chunk_total = buf[1023];
        int r = carry + incl - v;   // exclusive prefix + global carry
        if (i < n) { rowptr[i] = r; cursor[i] = r; }
        __syncthreads();
        if (tid == 0) carry += chunk_total;
        __syncthreads();
    }
    if (tid == 0) rowptr[n] = carry;
}

__global__ void scatter_kernel(const int* __restrict__ eidx, const int* __restrict__ flag,
                               int* __restrict__ cursor, int* __restrict__ csr_src, int E, int N) {
    int e = blockIdx.x * blockDim.x + threadIdx.x;
    if (e < E) {
        int is64 = *flag;
        int s = edge_elem(eidx, (size_t)e, is64);
        int d = edge_elem(eidx, (size_t)E + e, is64);
        if ((unsigned)d < (unsigned)N && (unsigned)s < (unsigned)N) {
            int pos = atomicAdd(&cursor[d], 1);
            csr_src[pos] = s;
        }
    }
}

// ---------------- GEMM: O[N,M] = X[N,K] * W[K,M], all f32 ----------------
__global__ void gemm_kernel(const float* __restrict__ X, const float* __restrict__ W,
                            float* __restrict__ O, int N, int K, int M) {
    __shared__ float As[16][64 + 1];
    __shared__ float Bs[16][64 + 1];
    int row0 = blockIdx.y * 64;
    int col0 = blockIdx.x * 64;
    int tid = threadIdx.x;
    int tr = tid >> 4, tc = tid & 15;
    float acc[4][4] = {};
    for (int k0 = 0; k0 < K; k0 += 16) {
        for (int i = tid; i < 64 * 16; i += 256) {
            int m = i >> 4, k = i & 15;
            int r = row0 + m;
            As[k][m] = (r < N) ? X[(size_t)r * K + k0 + k] : 0.f;
        }
        for (int i = tid; i < 16 * 64; i += 256) {
            int k = i >> 6, n = i & 63;
            Bs[k][n] = W[(size_t)(k0 + k) * M + col0 + n];
        }
        __syncthreads();
#pragma unroll
        for (int k = 0; k < 16; ++k) {
            float a[4], b[4];
#pragma unroll
            for (int j = 0; j < 4; ++j) a[j] = As[k][tr * 4 + j];
#pragma unroll
            for (int j = 0; j < 4; ++j) b[j] = Bs[k][tc * 4 + j];
#pragma unroll
            for (int i = 0; i < 4; ++i)
#pragma unroll
                for (int j = 0; j < 4; ++j) acc[i][j] += a[i] * b[j];
        }
        __syncthreads();
    }
#pragma unroll
    for (int i = 0; i < 4; ++i) {
        int r = row0 + tr * 4 + i;
        if (r < N) {
#pragma unroll
            for (int j = 0; j < 4; ++j)
                O[(size_t)r * M + col0 + tc * 4 + j] = acc[i][j];
        }
    }
}

// ---------------- attention logits per (node, head) ----------------
template <int C>
__global__ void al_kernel(const float* __restrict__ h,
                          const float* __restrict__ a_src,
                          const float* __restrict__ a_dst,
                          float* __restrict__ al_s, float* __restrict__ al_d, int N) {
    int idx = blockIdx.x * blockDim.x + threadIdx.x;  // n*HEADS + head
    if (idx >= N * HEADS) return;
    int n = idx >> 2, hd = idx & 3;
    const float* row = h + (size_t)n * HEADS * C + hd * C;
    float ss = 0.f, sd = 0.f;
#pragma unroll 8
    for (int c = 0; c < C; ++c) {
        float v = row[c];
        ss += v * a_src[hd * C + c];
        sd += v * a_dst[hd * C + c];
    }
    al_s[idx] = ss;
    al_d[idx] = sd;
}

// ---------------- per-node online-softmax aggregation (one wave per node) ----------------
template <int C, bool MEAN>
__global__ void aggregate_kernel(const float* __restrict__ h,
                                 const float* __restrict__ al_s, const float* __restrict__ al_d,
                                 const int* __restrict__ rowptr, const int* __restrict__ csr_src,
                                 const float* __restrict__ bias,
                                 float* __restrict__ outf, int N) {
    constexpr int VPT = 4 * C / 64;  // f32 elems per lane
    int wave = (blockIdx.x * blockDim.x + threadIdx.x) >> 6;
    int lane = threadIdx.x & 63;
    if (wave >= N) return;
    int n = wave;
    int head = lane >> 4;
    int c0 = (lane & 15) * VPT;

    float ald = al_d[n * HEADS + head];
    float m = -1.0e30f;  // finite sentinel: expf underflows to 0 on first edge
    float s = 0.f;
    float acc[VPT];
#pragma unroll
    for (int j = 0; j < VPT; ++j) acc[j] = 0.f;

    int beg = rowptr[n], end = rowptr[n + 1];
    for (int k = beg; k < end; ++k) {
        int src = csr_src[k];
        float e = al_s[src * HEADS + head] + ald;
        e = (e > 0.f) ? e : 0.2f * e;  // leaky relu
        float newm = fmaxf(m, e);
        float scale = expf(m - newm);
        float w = expf(e - newm);
        s = s * scale + w;
        const float* hr = h + (size_t)src * (HEADS * C) + head * C + c0;
        if (VPT == 4) {
            float4 v = *reinterpret_cast<const float4*>(hr);
            acc[0] = acc[0] * scale + w * v.x;
            acc[1] = acc[1] * scale + w * v.y;
            acc[2] = acc[2] * scale + w * v.z;
            acc[3] = acc[3] * scale + w * v.w;
        } else {
            float2 v = *reinterpret_cast<const float2*>(hr);
            acc[0] = acc[0] * scale + w * v.x;
            acc[1] = acc[1] * scale + w * v.y;
        }
        m = newm;
    }
    float inv = 1.f / (s + 1e-16f);
    if (!MEAN) {
        size_t o = (size_t)n * (HEADS * C) + head * C + c0;
#pragma unroll
        for (int j = 0; j < VPT; ++j)
            outf[o + j] = acc[j] * inv + bias[head * C + c0 + j];
    } else {
        float v[VPT];
#pragma unroll
        for (int j = 0; j < VPT; ++j) {
            float t = acc[j] * inv;
            t += __shfl_xor(t, 16);
            t += __shfl_xor(t, 32);
            v[j] = t * 0.25f + bias[c0 + j];
        }
        if (lane < 16) {
#pragma unroll
            for (int j = 0; j < VPT; ++j)
                outf[(size_t)n * C + c0 + j] = v[j];
        }
    }
}

// ---------------- launch ----------------
extern "C" void kernel_launch(void* const* d_in, const int* in_sizes, int n_in,
                              void* d_out, int out_size, void* d_ws, size_t ws_size,
                              hipStream_t stream) {
    const float* x      = (const float*)d_in[0];
    const int*   eidx   = (const int*)d_in[1];
    const float* W1     = (const float*)d_in[2];
    const float* a1_src = (const float*)d_in[3];
    const float* a1_dst = (const float*)d_in[4];
    const float* b1     = (const float*)d_in[5];
    const float* W2     = (const float*)d_in[6];
    const float* a2_src = (const float*)d_in[7];
    const float* a2_dst = (const float*)d_in[8];
    const float* b2     = (const float*)d_in[9];
    const float* W3     = (const float*)d_in[10];
    const float* a3_src = (const float*)d_in[11];
    const float* a3_dst = (const float*)d_in[12];
    const float* b3     = (const float*)d_in[13];
    float* out = (float*)d_out;  // reference output dtype is float32

    const int N = in_sizes[0] / 64;      // 50000
    const int E = in_sizes[1] / 2;       // 800000

    // workspace layout (floats then ints)
    float* buf1 = (float*)d_ws;                    // N*256
    float* buf2 = buf1 + (size_t)N * 256;          // N*256
    float* als  = buf2 + (size_t)N * 256;          // N*4
    float* ald  = als + (size_t)N * 4;             // N*4
    int* rowptr = (int*)(ald + (size_t)N * 4);     // N+1
    int* deg    = rowptr + (N + 1);                // N
    int* cursor = deg + N;                         // N
    int* csr    = cursor + N;                      // E
    int* flag   = csr + E;                         // 1

    // ---- detect edge dtype + build CSR (by dst) once, shared by all 3 layers ----
    detect_kernel<<<1, 64, 0, stream>>>(eidx, flag);
    hipMemsetAsync(deg, 0, (size_t)N * sizeof(int), stream);
    deg_kernel<<<(E + 255) / 256, 256, 0, stream>>>(eidx, flag, deg, E, N);
    scan_kernel<<<1, 1024, 0, stream>>>(deg, rowptr, cursor, N);
    scatter_kernel<<<(E + 255) / 256, 256, 0, stream>>>(eidx, flag, cursor, csr, E, N);

    const int rowBlocks = (N + 63) / 64;
    const int alBlocks  = (N * HEADS + 255) / 256;
    const int aggBlocks = (N + 3) / 4;  // 4 waves per 256-thread block

    // ---- layer 1: 64 -> 4x64 concat (256) ----
    gemm_kernel<<<dim3(256 / 64, rowBlocks), 256, 0, stream>>>(x, W1, buf1, N, 64, 256);
    al_kernel<64><<<alBlocks, 256, 0, stream>>>(buf1, a1_src, a1_dst, als, ald, N);
    aggregate_kernel<64, false><<<aggBlocks, 256, 0, stream>>>(buf1, als, ald, rowptr, csr, b1, buf2, N);

    // ---- layer 2: 256 -> 4x32 concat (128) ----
    gemm_kernel<<<dim3(128 / 64, rowBlocks), 256, 0, stream>>>(buf2, W2, buf1, N, 256, 128);
    al_kernel<32><<<alBlocks, 256, 0, stream>>>(buf1, a2_src, a2_dst, als, ald, N);
    float* out2 = buf1 + (size_t)N * 128;  // upper half of buf1 (no overlap with h2)
    aggregate_kernel<32, false><<<aggBlocks, 256, 0, stream>>>(buf1, als, ald, rowptr, csr, b2, out2, N);

    // ---- layer 3 (recon): 128 -> 4x64, mean over heads (64) ----
    gemm_kernel<<<dim3(256 / 64, rowBlocks), 256, 0, stream>>>(out2, W3, buf2, N, 128, 256);
    al_kernel<64><<<alBlocks, 256, 0, stream>>>(buf2, a3_src, a3_dst, als, ald, N);
    aggregate_kernel<64, true><<<aggBlocks, 256, 0, stream>>>(buf2, als, ald, rowptr, csr, b3, out, N);
}

// Round 6
// 626.184 us; speedup vs baseline: 1.3361x; 1.3361x over previous
//
#include <hip/hip_runtime.h>
#include <hip/hip_bf16.h>

#define HEADS 4

// ---------------- edge dtype detection (int32 vs int64 layout) ----------------
__global__ void detect_kernel(const int* __restrict__ eidx, int* __restrict__ flag) {
    if (blockIdx.x == 0 && threadIdx.x == 0) {
        int orv = 0;
        for (int i = 0; i < 256; ++i) orv |= eidx[2 * i + 1];
        *flag = (orv == 0) ? 1 : 0;  // 1 = int64 layout
    }
}

__device__ __forceinline__ int edge_elem(const int* e, size_t idx, int is64) {
    return is64 ? e[2 * idx] : e[idx];
}

// ---------------- CSR build ----------------
__global__ void deg_kernel(const int* __restrict__ eidx, const int* __restrict__ flag,
                           int* __restrict__ deg, int E, int N) {
    int e = blockIdx.x * blockDim.x + threadIdx.x;
    if (e < E) {
        int is64 = *flag;
        int d = edge_elem(eidx, (size_t)E + e, is64);
        if ((unsigned)d < (unsigned)N) atomicAdd(&deg[d], 1);
    }
}

// reduce 1024 deg values per block -> bsum[block]
__global__ void reduce_kernel(const int* __restrict__ deg, int* __restrict__ bsum, int n) {
    __shared__ int sdata[256];
    int base = blockIdx.x * 1024;
    int t = threadIdx.x;
    int v = 0;
#pragma unroll
    for (int j = 0; j < 4; ++j) {
        int i = base + t + j * 256;
        if (i < n) v += deg[i];
    }
    sdata[t] = v;
    __syncthreads();
    for (int off = 128; off > 0; off >>= 1) {
        if (t < off) sdata[t] += sdata[t + off];
        __syncthreads();
    }
    if (t == 0) bsum[blockIdx.x] = sdata[0];
}

// single-wave exclusive scan of block sums (+ total -> *totalp)
__global__ void scan_bsum_kernel(const int* __restrict__ bsum, int* __restrict__ boff,
                                 int nb, int* __restrict__ totalp) {
    int lane = threadIdx.x;  // 64 threads
    int carry = 0;
    for (int base = 0; base < nb; base += 64) {
        int i = base + lane;
        int v = (i < nb) ? bsum[i] : 0;
        int inc = v;
        for (int off = 1; off < 64; off <<= 1) {
            int tt = __shfl_up(inc, off);
            if (lane >= off) inc += tt;
        }
        if (i < nb) boff[i] = carry + inc - v;
        carry += __shfl(inc, 63);
    }
    if (lane == 0) *totalp = carry;
}

// per-block exclusive scan of deg (1024 elems/block) with block offset
__global__ void block_scan_kernel(const int* __restrict__ deg, const int* __restrict__ boff,
                                  int* __restrict__ rowptr, int* __restrict__ cursor, int n) {
    __shared__ int wsum[4];
    int base = blockIdx.x * 1024;
    int t = threadIdx.x;  // 256
    int lane = t & 63, w = t >> 6;
    int v[4];
    int lsum = 0;
#pragma unroll
    for (int j = 0; j < 4; ++j) {
        int i = base + t * 4 + j;
        v[j] = (i < n) ? deg[i] : 0;
        lsum += v[j];
    }
    int inc = lsum;
    for (int off = 1; off < 64; off <<= 1) {
        int tt = __shfl_up(inc, off);
        if (lane >= off) inc += tt;
    }
    if (lane == 63) wsum[w] = inc;
    __syncthreads();
    int woff = 0;
    for (int i = 0; i < w; ++i) woff += wsum[i];
    int ex = boff[blockIdx.x] + woff + inc - lsum;
#pragma unroll
    for (int j = 0; j < 4; ++j) {
        int i = base + t * 4 + j;
        if (i < n) { rowptr[i] = ex; cursor[i] = ex; }
        ex += v[j];
    }
}

__global__ void scatter_kernel(const int* __restrict__ eidx, const int* __restrict__ flag,
                               int* __restrict__ cursor, int* __restrict__ csr_src, int E, int N) {
    int e = blockIdx.x * blockDim.x + threadIdx.x;
    if (e < E) {
        int is64 = *flag;
        int s = edge_elem(eidx, (size_t)e, is64);
        int d = edge_elem(eidx, (size_t)E + e, is64);
        if ((unsigned)d < (unsigned)N && (unsigned)s < (unsigned)N) {
            int pos = atomicAdd(&cursor[d], 1);
            csr_src[pos] = s;
        }
    }
}

// ---------------- GEMM: O[N,M] = X[N,K] * W[K,M], 128x128 tile, 8x8 micro ----------------
// K, M multiples of 16/128 resp. guaranteed by caller (K in {64,256,128}, M in {256,128}).
__global__ __launch_bounds__(256) void gemm_kernel(const float* __restrict__ X,
                                                   const float* __restrict__ W,
                                                   float* __restrict__ O,
                                                   int N, int K, int M) {
    __shared__ float As[16][132];  // pad 132: float4-aligned rows, conflict-light
    __shared__ float Bs[16][132];
    int row0 = blockIdx.y * 128;
    int col0 = blockIdx.x * 128;
    int tid = threadIdx.x;
    int tx = tid & 15;   // col group
    int ty = tid >> 4;   // row group
    float acc[8][8] = {};
    for (int k0 = 0; k0 < K; k0 += 16) {
        // stage A: rows row0..+127, cols k0..+15, transposed into As[k][r]
        for (int i = tid; i < 512; i += 256) {
            int r = i >> 2;
            int kc = (i & 3) * 4;
            int gr = row0 + r;
            float4 v = make_float4(0.f, 0.f, 0.f, 0.f);
            if (gr < N) v = *reinterpret_cast<const float4*>(&X[(size_t)gr * K + k0 + kc]);
            As[kc + 0][r] = v.x;
            As[kc + 1][r] = v.y;
            As[kc + 2][r] = v.z;
            As[kc + 3][r] = v.w;
        }
        // stage B: rows k0..+15, cols col0..+127
        for (int i = tid; i < 512; i += 256) {
            int k = i >> 5;
            int c4 = (i & 31) * 4;
            float4 v = *reinterpret_cast<const float4*>(&W[(size_t)(k0 + k) * M + col0 + c4]);
            *reinterpret_cast<float4*>(&Bs[k][c4]) = v;
        }
        __syncthreads();
#pragma unroll
        for (int k = 0; k < 16; ++k) {
            float4 a0 = *reinterpret_cast<const float4*>(&As[k][ty * 4]);
            float4 a1 = *reinterpret_cast<const float4*>(&As[k][64 + ty * 4]);
            float4 b0 = *reinterpret_cast<const float4*>(&Bs[k][tx * 4]);
            float4 b1 = *reinterpret_cast<const float4*>(&Bs[k][64 + tx * 4]);
            float ar[8] = {a0.x, a0.y, a0.z, a0.w, a1.x, a1.y, a1.z, a1.w};
            float br[8] = {b0.x, b0.y, b0.z, b0.w, b1.x, b1.y, b1.z, b1.w};
#pragma unroll
            for (int i = 0; i < 8; ++i)
#pragma unroll
                for (int j = 0; j < 8; ++j) acc[i][j] += ar[i] * br[j];
        }
        __syncthreads();
    }
    // epilogue
#pragma unroll
    for (int ih = 0; ih < 2; ++ih) {
#pragma unroll
        for (int i = 0; i < 4; ++i) {
            int r = row0 + ih * 64 + ty * 4 + i;
            if (r < N) {
                float* orow = &O[(size_t)r * M + col0];
#pragma unroll
                for (int jh = 0; jh < 2; ++jh) {
                    float4 v = make_float4(acc[ih * 4 + i][jh * 4 + 0], acc[ih * 4 + i][jh * 4 + 1],
                                           acc[ih * 4 + i][jh * 4 + 2], acc[ih * 4 + i][jh * 4 + 3]);
                    *reinterpret_cast<float4*>(&orow[jh * 64 + tx * 4]) = v;
                }
            }
        }
    }
}

// ---------------- attention logits per (node, head) ----------------
template <int C>
__global__ void al_kernel(const float* __restrict__ h,
                          const float* __restrict__ a_src,
                          const float* __restrict__ a_dst,
                          float* __restrict__ al_s, float* __restrict__ al_d, int N) {
    int idx = blockIdx.x * blockDim.x + threadIdx.x;  // n*HEADS + head
    if (idx >= N * HEADS) return;
    int n = idx >> 2, hd = idx & 3;
    const float* row = h + (size_t)n * HEADS * C + hd * C;
    float ss = 0.f, sd = 0.f;
#pragma unroll
    for (int c = 0; c < C; c += 4) {
        float4 v = *reinterpret_cast<const float4*>(&row[c]);
        float4 as = *reinterpret_cast<const float4*>(&a_src[hd * C + c]);
        float4 ad = *reinterpret_cast<const float4*>(&a_dst[hd * C + c]);
        ss += v.x * as.x + v.y * as.y + v.z * as.z + v.w * as.w;
        sd += v.x * ad.x + v.y * ad.y + v.z * ad.z + v.w * ad.w;
    }
    al_s[idx] = ss;
    al_d[idx] = sd;
}

// ---------------- per-node softmax aggregation (one wave per node) ----------------
// No online max: logits are bounded (|e| ~ few units), exp(e) cannot overflow f32;
// identical math to max-subtracted softmax.
template <int C, bool MEAN>
__global__ void aggregate_kernel(const float* __restrict__ h,
                                 const float* __restrict__ al_s, const float* __restrict__ al_d,
                                 const int* __restrict__ rowptr, const int* __restrict__ csr_src,
                                 const float* __restrict__ bias,
                                 float* __restrict__ outf, int N) {
    constexpr int VPT = 4 * C / 64;  // 4 (C=64) or 2 (C=32)
    int wave = (blockIdx.x * blockDim.x + threadIdx.x) >> 6;
    int lane = threadIdx.x & 63;
    if (wave >= N) return;
    int head = lane >> 4;
    int c0 = (lane & 15) * VPT;
    const float* hb = h + head * C + c0;

    float ald = al_d[wave * HEADS + head];
    float s = 0.f;
    float acc[VPT];
#pragma unroll
    for (int j = 0; j < VPT; ++j) acc[j] = 0.f;

    int beg = rowptr[wave], end = rowptr[wave + 1];
    int k = beg;
    for (; k + 2 <= end; k += 2) {
        int s0 = csr_src[k], s1 = csr_src[k + 1];
        float e0 = al_s[s0 * HEADS + head] + ald;
        float e1 = al_s[s1 * HEADS + head] + ald;
        const float* p0 = hb + (size_t)s0 * (HEADS * C);
        const float* p1 = hb + (size_t)s1 * (HEADS * C);
        e0 = fmaxf(e0, 0.2f * e0);  // leaky relu
        e1 = fmaxf(e1, 0.2f * e1);
        float w0 = __expf(e0), w1 = __expf(e1);
        if (VPT == 4) {
            float4 v0 = *reinterpret_cast<const float4*>(p0);
            float4 v1 = *reinterpret_cast<const float4*>(p1);
            s += w0 + w1;
            acc[0] += w0 * v0.x; acc[1] += w0 * v0.y; acc[2] += w0 * v0.z; acc[3] += w0 * v0.w;
            acc[0] += w1 * v1.x; acc[1] += w1 * v1.y; acc[2] += w1 * v1.z; acc[3] += w1 * v1.w;
        } else {
            float2 v0 = *reinterpret_cast<const float2*>(p0);
            float2 v1 = *reinterpret_cast<const float2*>(p1);
            s += w0 + w1;
            acc[0] += w0 * v0.x; acc[1] += w0 * v0.y;
            acc[0] += w1 * v1.x; acc[1] += w1 * v1.y;
        }
    }
    if (k < end) {
        int s0 = csr_src[k];
        float e0 = al_s[s0 * HEADS + head] + ald;
        e0 = fmaxf(e0, 0.2f * e0);
        float w0 = __expf(e0);
        const float* p0 = hb + (size_t)s0 * (HEADS * C);
        s += w0;
        if (VPT == 4) {
            float4 v0 = *reinterpret_cast<const float4*>(p0);
            acc[0] += w0 * v0.x; acc[1] += w0 * v0.y; acc[2] += w0 * v0.z; acc[3] += w0 * v0.w;
        } else {
            float2 v0 = *reinterpret_cast<const float2*>(p0);
            acc[0] += w0 * v0.x; acc[1] += w0 * v0.y;
        }
    }

    float inv = 1.f / (s + 1e-16f);
    if (!MEAN) {
        size_t o = (size_t)wave * (HEADS * C) + head * C + c0;
#pragma unroll
        for (int j = 0; j < VPT; ++j)
            outf[o + j] = acc[j] * inv + bias[head * C + c0 + j];
    } else {
        float v[VPT];
#pragma unroll
        for (int j = 0; j < VPT; ++j) {
            float t = acc[j] * inv;
            t += __shfl_xor(t, 16);
            t += __shfl_xor(t, 32);
            v[j] = t * 0.25f + bias[c0 + j];
        }
        if (lane < 16) {
#pragma unroll
            for (int j = 0; j < VPT; ++j)
                outf[(size_t)wave * C + c0 + j] = v[j];
        }
    }
}

// ---------------- launch ----------------
extern "C" void kernel_launch(void* const* d_in, const int* in_sizes, int n_in,
                              void* d_out, int out_size, void* d_ws, size_t ws_size,
                              hipStream_t stream) {
    const float* x      = (const float*)d_in[0];
    const int*   eidx   = (const int*)d_in[1];
    const float* W1     = (const float*)d_in[2];
    const float* a1_src = (const float*)d_in[3];
    const float* a1_dst = (const float*)d_in[4];
    const float* b1     = (const float*)d_in[5];
    const float* W2     = (const float*)d_in[6];
    const float* a2_src = (const float*)d_in[7];
    const float* a2_dst = (const float*)d_in[8];
    const float* b2     = (const float*)d_in[9];
    const float* W3     = (const float*)d_in[10];
    const float* a3_src = (const float*)d_in[11];
    const float* a3_dst = (const float*)d_in[12];
    const float* b3     = (const float*)d_in[13];
    float* out = (float*)d_out;

    const int N = in_sizes[0] / 64;      // 50000
    const int E = in_sizes[1] / 2;       // 800000
    const int NB = (N + 1023) / 1024;    // scan blocks (49)

    // workspace layout
    float* buf1 = (float*)d_ws;                    // N*256
    float* buf2 = buf1 + (size_t)N * 256;          // N*256
    float* als  = buf2 + (size_t)N * 256;          // N*4
    float* ald  = als + (size_t)N * 4;             // N*4
    int* rowptr = (int*)(ald + (size_t)N * 4);     // N+1
    int* deg    = rowptr + (N + 1);                // N
    int* cursor = deg + N;                         // N
    int* csr    = cursor + N;                      // E
    int* flag   = csr + E;                         // 1
    int* bsum   = flag + 1;                        // NB
    int* boff   = bsum + NB;                       // NB

    // ---- detect edge dtype + build CSR (by dst) once, shared by all 3 layers ----
    detect_kernel<<<1, 64, 0, stream>>>(eidx, flag);
    hipMemsetAsync(deg, 0, (size_t)N * sizeof(int), stream);
    deg_kernel<<<(E + 255) / 256, 256, 0, stream>>>(eidx, flag, deg, E, N);
    reduce_kernel<<<NB, 256, 0, stream>>>(deg, bsum, N);
    scan_bsum_kernel<<<1, 64, 0, stream>>>(bsum, boff, NB, rowptr + N);
    block_scan_kernel<<<NB, 256, 0, stream>>>(deg, boff, rowptr, cursor, N);
    scatter_kernel<<<(E + 255) / 256, 256, 0, stream>>>(eidx, flag, cursor, csr, E, N);

    const int rowBlocks = (N + 127) / 128;
    const int alBlocks  = (N * HEADS + 255) / 256;
    const int aggBlocks = (N + 3) / 4;  // 4 waves per 256-thread block

    // ---- layer 1: 64 -> 4x64 concat (256) ----
    gemm_kernel<<<dim3(256 / 128, rowBlocks), 256, 0, stream>>>(x, W1, buf1, N, 64, 256);
    al_kernel<64><<<alBlocks, 256, 0, stream>>>(buf1, a1_src, a1_dst, als, ald, N);
    aggregate_kernel<64, false><<<aggBlocks, 256, 0, stream>>>(buf1, als, ald, rowptr, csr, b1, buf2, N);

    // ---- layer 2: 256 -> 4x32 concat (128) ----
    gemm_kernel<<<dim3(128 / 128, rowBlocks), 256, 0, stream>>>(buf2, W2, buf1, N, 256, 128);
    al_kernel<32><<<alBlocks, 256, 0, stream>>>(buf1, a2_src, a2_dst, als, ald, N);
    float* out2 = buf1 + (size_t)N * 128;  // upper half of buf1 (no overlap with h2)
    aggregate_kernel<32, false><<<aggBlocks, 256, 0, stream>>>(buf1, als, ald, rowptr, csr, b2, out2, N);

    // ---- layer 3 (recon): 128 -> 4x64, mean over heads (64) ----
    gemm_kernel<<<dim3(256 / 128, rowBlocks), 256, 0, stream>>>(out2, W3, buf2, N, 128, 256);
    al_kernel<64><<<alBlocks, 256, 0, stream>>>(buf2, a3_src, a3_dst, als, ald, N);
    aggregate_kernel<64, true><<<aggBlocks, 256, 0, stream>>>(buf2, als, ald, rowptr, csr, b3, out, N);
}

// Round 7
// 618.568 us; speedup vs baseline: 1.3525x; 1.0123x over previous
//
#include <hip/hip_runtime.h>
#include <hip/hip_bf16.h>

#define HEADS 4

// ---------------- edge dtype detection (int32 vs int64 layout) ----------------
__global__ void detect_kernel(const int* __restrict__ eidx, int* __restrict__ flag) {
    if (blockIdx.x == 0 && threadIdx.x == 0) {
        int orv = 0;
        for (int i = 0; i < 256; ++i) orv |= eidx[2 * i + 1];
        *flag = (orv == 0) ? 1 : 0;  // 1 = int64 layout
    }
}

__device__ __forceinline__ int edge_elem(const int* e, size_t idx, int is64) {
    return is64 ? e[2 * idx] : e[idx];
}

// ---------------- CSR build ----------------
__global__ void deg_kernel(const int* __restrict__ eidx, const int* __restrict__ flag,
                           int* __restrict__ deg, int E, int N) {
    int e = blockIdx.x * blockDim.x + threadIdx.x;
    if (e < E) {
        int is64 = *flag;
        int d = edge_elem(eidx, (size_t)E + e, is64);
        if ((unsigned)d < (unsigned)N) atomicAdd(&deg[d], 1);
    }
}

__global__ void reduce_kernel(const int* __restrict__ deg, int* __restrict__ bsum, int n) {
    __shared__ int sdata[256];
    int base = blockIdx.x * 1024;
    int t = threadIdx.x;
    int v = 0;
#pragma unroll
    for (int j = 0; j < 4; ++j) {
        int i = base + t + j * 256;
        if (i < n) v += deg[i];
    }
    sdata[t] = v;
    __syncthreads();
    for (int off = 128; off > 0; off >>= 1) {
        if (t < off) sdata[t] += sdata[t + off];
        __syncthreads();
    }
    if (t == 0) bsum[blockIdx.x] = sdata[0];
}

__global__ void scan_bsum_kernel(const int* __restrict__ bsum, int* __restrict__ boff,
                                 int nb, int* __restrict__ totalp) {
    int lane = threadIdx.x;  // 64
    int carry = 0;
    for (int base = 0; base < nb; base += 64) {
        int i = base + lane;
        int v = (i < nb) ? bsum[i] : 0;
        int inc = v;
        for (int off = 1; off < 64; off <<= 1) {
            int tt = __shfl_up(inc, off);
            if (lane >= off) inc += tt;
        }
        if (i < nb) boff[i] = carry + inc - v;
        carry += __shfl(inc, 63);
    }
    if (lane == 0) *totalp = carry;
}

__global__ void block_scan_kernel(const int* __restrict__ deg, const int* __restrict__ boff,
                                  int* __restrict__ rowptr, int* __restrict__ cursor, int n) {
    __shared__ int wsum[4];
    int base = blockIdx.x * 1024;
    int t = threadIdx.x;  // 256
    int lane = t & 63, w = t >> 6;
    int v[4];
    int lsum = 0;
#pragma unroll
    for (int j = 0; j < 4; ++j) {
        int i = base + t * 4 + j;
        v[j] = (i < n) ? deg[i] : 0;
        lsum += v[j];
    }
    int inc = lsum;
    for (int off = 1; off < 64; off <<= 1) {
        int tt = __shfl_up(inc, off);
        if (lane >= off) inc += tt;
    }
    if (lane == 63) wsum[w] = inc;
    __syncthreads();
    int woff = 0;
    for (int i = 0; i < w; ++i) woff += wsum[i];
    int ex = boff[blockIdx.x] + woff + inc - lsum;
#pragma unroll
    for (int j = 0; j < 4; ++j) {
        int i = base + t * 4 + j;
        if (i < n) { rowptr[i] = ex; cursor[i] = ex; }
        ex += v[j];
    }
}

__global__ void scatter_kernel(const int* __restrict__ eidx, const int* __restrict__ flag,
                               int* __restrict__ cursor, int* __restrict__ csr_src, int E, int N) {
    int e = blockIdx.x * blockDim.x + threadIdx.x;
    if (e < E) {
        int is64 = *flag;
        int s = edge_elem(eidx, (size_t)e, is64);
        int d = edge_elem(eidx, (size_t)E + e, is64);
        if ((unsigned)d < (unsigned)N && (unsigned)s < (unsigned)N) {
            int pos = atomicAdd(&cursor[d], 1);
            csr_src[pos] = s;
        }
    }
}

// ---------------- projected attention vectors: p[h][k] = sum_c W[k, h*Ch+c] * a[h][c] ----------------
__global__ void proj_kernel(const float* __restrict__ W, const float* __restrict__ as,
                            const float* __restrict__ ad, float* __restrict__ ps,
                            float* __restrict__ pd, int K, int M, int Ch) {
    int idx = blockIdx.x * blockDim.x + threadIdx.x;
    if (idx >= 4 * K) return;
    int h = idx / K, k = idx % K;
    float ss = 0.f, sd = 0.f;
    for (int c = 0; c < Ch; ++c) {
        float w = W[(size_t)k * M + h * Ch + c];
        ss += w * as[h * Ch + c];
        sd += w * ad[h * Ch + c];
    }
    ps[idx] = ss;
    pd[idx] = sd;
}

// ---------------- logits from raw features: als[n,h] = x[n,:] . ps[h,:] ----------------
template <int K>
__global__ void alx_kernel(const float* __restrict__ x, const float* __restrict__ ps,
                           const float* __restrict__ pd, float* __restrict__ als,
                           float* __restrict__ ald, int N) {
    int idx = blockIdx.x * blockDim.x + threadIdx.x;  // n*4+h
    if (idx >= N * 4) return;
    int n = idx >> 2, h = idx & 3;
    const float* row = x + (size_t)n * K;
    const float* vs = ps + h * K;
    const float* vd = pd + h * K;
    float ss = 0.f, sd = 0.f;
#pragma unroll
    for (int c = 0; c < K; c += 4) {
        float4 v = *reinterpret_cast<const float4*>(&row[c]);
        float4 a = *reinterpret_cast<const float4*>(&vs[c]);
        float4 b = *reinterpret_cast<const float4*>(&vd[c]);
        ss += v.x * a.x + v.y * a.y + v.z * a.z + v.w * a.w;
        sd += v.x * b.x + v.y * b.y + v.z * b.z + v.w * b.w;
    }
    als[idx] = ss;
    ald[idx] = sd;
}

// ---------------- logits from interleaved head features (layer 2 / fallback) ----------------
template <int C>
__global__ void al_kernel(const float* __restrict__ h,
                          const float* __restrict__ a_src,
                          const float* __restrict__ a_dst,
                          float* __restrict__ al_s, float* __restrict__ al_d, int N) {
    int idx = blockIdx.x * blockDim.x + threadIdx.x;
    if (idx >= N * HEADS) return;
    int n = idx >> 2, hd = idx & 3;
    const float* row = h + (size_t)n * HEADS * C + hd * C;
    float ss = 0.f, sd = 0.f;
#pragma unroll
    for (int c = 0; c < C; c += 4) {
        float4 v = *reinterpret_cast<const float4*>(&row[c]);
        float4 as = *reinterpret_cast<const float4*>(&a_src[hd * C + c]);
        float4 ad = *reinterpret_cast<const float4*>(&a_dst[hd * C + c]);
        ss += v.x * as.x + v.y * as.y + v.z * as.z + v.w * as.w;
        sd += v.x * ad.x + v.y * ad.y + v.z * ad.z + v.w * ad.w;
    }
    al_s[idx] = ss;
    al_d[idx] = sd;
}

// ---------------- pre-aggregation: agg[i, h*K + c] = softmax-weighted sum of x[j, c] ----------------
// K = input channels (shared across heads). One wave per node.
template <int K>
__global__ void preagg_kernel(const float* __restrict__ x, const float* __restrict__ als,
                              const float* __restrict__ ald, const int* __restrict__ rowptr,
                              const int* __restrict__ csr, float* __restrict__ agg, int N) {
    constexpr int V = K / 64;  // floats per lane (1 or 2)
    int wave = (blockIdx.x * blockDim.x + threadIdx.x) >> 6;
    int lane = threadIdx.x & 63;
    if (wave >= N) return;
    float4 aldv = *reinterpret_cast<const float4*>(&ald[wave * 4]);
    float s0 = 0.f, s1 = 0.f, s2 = 0.f, s3 = 0.f;
    float acc[4][V] = {};
    int beg = rowptr[wave], end = rowptr[wave + 1];
    for (int k = beg; k < end; ++k) {
        int j = csr[k];
        float4 e = *reinterpret_cast<const float4*>(&als[j * 4]);
        e.x += aldv.x; e.y += aldv.y; e.z += aldv.z; e.w += aldv.w;
        e.x = fmaxf(e.x, 0.2f * e.x); e.y = fmaxf(e.y, 0.2f * e.y);
        e.z = fmaxf(e.z, 0.2f * e.z); e.w = fmaxf(e.w, 0.2f * e.w);
        float w0 = __expf(e.x), w1 = __expf(e.y), w2 = __expf(e.z), w3 = __expf(e.w);
        s0 += w0; s1 += w1; s2 += w2; s3 += w3;
        if (V == 1) {
            float v = x[(size_t)j * K + lane];
            acc[0][0] += w0 * v; acc[1][0] += w1 * v;
            acc[2][0] += w2 * v; acc[3][0] += w3 * v;
        } else {
            float2 v = *reinterpret_cast<const float2*>(&x[(size_t)j * K + lane * 2]);
            acc[0][0] += w0 * v.x; acc[0][1] += w0 * v.y;
            acc[1][0] += w1 * v.x; acc[1][1] += w1 * v.y;
            acc[2][0] += w2 * v.x; acc[2][1] += w2 * v.y;
            acc[3][0] += w3 * v.x; acc[3][1] += w3 * v.y;
        }
    }
    float inv[4] = {1.f / (s0 + 1e-16f), 1.f / (s1 + 1e-16f),
                    1.f / (s2 + 1e-16f), 1.f / (s3 + 1e-16f)};
    size_t o = (size_t)wave * 4 * K;
#pragma unroll
    for (int h = 0; h < 4; ++h)
#pragma unroll
        for (int j = 0; j < V; ++j)
            agg[o + h * K + lane * V + j] = acc[h][j] * inv[h];
}

// ---------------- post-GEMM aggregation (layer 2 + fallback layer 3) ----------------
template <int C, bool MEAN>
__global__ void aggregate_kernel(const float* __restrict__ h,
                                 const float* __restrict__ al_s, const float* __restrict__ al_d,
                                 const int* __restrict__ rowptr, const int* __restrict__ csr_src,
                                 const float* __restrict__ bias,
                                 float* __restrict__ outf, int N) {
    constexpr int VPT = 4 * C / 64;
    int wave = (blockIdx.x * blockDim.x + threadIdx.x) >> 6;
    int lane = threadIdx.x & 63;
    if (wave >= N) return;
    int head = lane >> 4;
    int c0 = (lane & 15) * VPT;
    const float* hb = h + head * C + c0;

    float ald = al_d[wave * HEADS + head];
    float s = 0.f;
    float acc[VPT];
#pragma unroll
    for (int j = 0; j < VPT; ++j) acc[j] = 0.f;

    int beg = rowptr[wave], end = rowptr[wave + 1];
    int k = beg;
    for (; k + 2 <= end; k += 2) {
        int s0 = csr_src[k], s1 = csr_src[k + 1];
        float e0 = al_s[s0 * HEADS + head] + ald;
        float e1 = al_s[s1 * HEADS + head] + ald;
        const float* p0 = hb + (size_t)s0 * (HEADS * C);
        const float* p1 = hb + (size_t)s1 * (HEADS * C);
        e0 = fmaxf(e0, 0.2f * e0);
        e1 = fmaxf(e1, 0.2f * e1);
        float w0 = __expf(e0), w1 = __expf(e1);
        s += w0 + w1;
        if (VPT == 4) {
            float4 v0 = *reinterpret_cast<const float4*>(p0);
            float4 v1 = *reinterpret_cast<const float4*>(p1);
            acc[0] += w0 * v0.x; acc[1] += w0 * v0.y; acc[2] += w0 * v0.z; acc[3] += w0 * v0.w;
            acc[0] += w1 * v1.x; acc[1] += w1 * v1.y; acc[2] += w1 * v1.z; acc[3] += w1 * v1.w;
        } else {
            float2 v0 = *reinterpret_cast<const float2*>(p0);
            float2 v1 = *reinterpret_cast<const float2*>(p1);
            acc[0] += w0 * v0.x; acc[1] += w0 * v0.y;
            acc[0] += w1 * v1.x; acc[1] += w1 * v1.y;
        }
    }
    if (k < end) {
        int s0 = csr_src[k];
        float e0 = al_s[s0 * HEADS + head] + ald;
        e0 = fmaxf(e0, 0.2f * e0);
        float w0 = __expf(e0);
        const float* p0 = hb + (size_t)s0 * (HEADS * C);
        s += w0;
        if (VPT == 4) {
            float4 v0 = *reinterpret_cast<const float4*>(p0);
            acc[0] += w0 * v0.x; acc[1] += w0 * v0.y; acc[2] += w0 * v0.z; acc[3] += w0 * v0.w;
        } else {
            float2 v0 = *reinterpret_cast<const float2*>(p0);
            acc[0] += w0 * v0.x; acc[1] += w0 * v0.y;
        }
    }

    float inv = 1.f / (s + 1e-16f);
    if (!MEAN) {
        size_t o = (size_t)wave * (HEADS * C) + head * C + c0;
#pragma unroll
        for (int j = 0; j < VPT; ++j)
            outf[o + j] = acc[j] * inv + bias[head * C + c0 + j];
    } else {
        float v[VPT];
#pragma unroll
        for (int j = 0; j < VPT; ++j) {
            float t = acc[j] * inv;
            t += __shfl_xor(t, 16);
            t += __shfl_xor(t, 32);
            v[j] = t * 0.25f + bias[c0 + j];
        }
        if (lane < 16) {
#pragma unroll
            for (int j = 0; j < VPT; ++j)
                outf[(size_t)wave * C + c0 + j] = v[j];
        }
    }
}

// ---------------- W3 restack: Wstk[h*128+k][c] = W3[k][h*64+c] * 0.25 ----------------
__global__ void wstk_kernel(const float* __restrict__ W3, float* __restrict__ Wstk) {
    int idx = blockIdx.x * blockDim.x + threadIdx.x;  // 512*64
    if (idx >= 512 * 64) return;
    int c = idx & 63;
    int hk = idx >> 6;
    int h = hk >> 7, k = hk & 127;
    Wstk[idx] = W3[(size_t)k * 256 + h * 64 + c] * 0.25f;
}

// ---------------- GEMM: O[N, col0+0..63] = A[N, aOff..aOff+K) @ B[0..K, col0..]  (BM=128, BN=64) ----
// aSel=1: per-col-block A column offset (per-head GEMM, agg layout [h*K + k]).
__global__ __launch_bounds__(256) void gemm64_kernel(const float* __restrict__ A, int lda, int aSel,
                                                     const float* __restrict__ B, int ldb,
                                                     float* __restrict__ O, int ldo,
                                                     const float* __restrict__ bias,
                                                     int N, int K) {
    __shared__ float As[16][132];
    __shared__ float Bs[16][68];
    int col0 = blockIdx.x * 64;
    int row0 = blockIdx.y * 128;
    int aOff = aSel ? col0 : 0;
    int tid = threadIdx.x;
    int tx = tid & 15, ty = tid >> 4;
    float acc[8][4] = {};
    for (int k0 = 0; k0 < K; k0 += 16) {
        for (int i = tid; i < 512; i += 256) {
            int r = i >> 2, kc = (i & 3) * 4;
            int gr = row0 + r;
            float4 v = make_float4(0.f, 0.f, 0.f, 0.f);
            if (gr < N) v = *reinterpret_cast<const float4*>(&A[(size_t)gr * lda + aOff + k0 + kc]);
            As[kc + 0][r] = v.x; As[kc + 1][r] = v.y;
            As[kc + 2][r] = v.z; As[kc + 3][r] = v.w;
        }
        {
            int k = tid >> 4, c4 = (tid & 15) * 4;
            float4 v = *reinterpret_cast<const float4*>(&B[(size_t)(k0 + k) * ldb + col0 + c4]);
            *reinterpret_cast<float4*>(&Bs[k][c4]) = v;
        }
        __syncthreads();
#pragma unroll
        for (int k = 0; k < 16; ++k) {
            float4 a0 = *reinterpret_cast<const float4*>(&As[k][ty * 8]);
            float4 a1 = *reinterpret_cast<const float4*>(&As[k][ty * 8 + 4]);
            float4 b0 = *reinterpret_cast<const float4*>(&Bs[k][tx * 4]);
            float ar[8] = {a0.x, a0.y, a0.z, a0.w, a1.x, a1.y, a1.z, a1.w};
            float br[4] = {b0.x, b0.y, b0.z, b0.w};
#pragma unroll
            for (int i = 0; i < 8; ++i)
#pragma unroll
                for (int j = 0; j < 4; ++j) acc[i][j] += ar[i] * br[j];
        }
        __syncthreads();
    }
    float4 bv = make_float4(0.f, 0.f, 0.f, 0.f);
    if (bias) bv = *reinterpret_cast<const float4*>(&bias[col0 + tx * 4]);
#pragma unroll
    for (int i = 0; i < 8; ++i) {
        int r = row0 + ty * 8 + i;
        if (r < N) {
            float4 v = make_float4(acc[i][0] + bv.x, acc[i][1] + bv.y,
                                   acc[i][2] + bv.z, acc[i][3] + bv.w);
            *reinterpret_cast<float4*>(&O[(size_t)r * ldo + col0 + tx * 4]) = v;
        }
    }
}

// ---------------- launch ----------------
extern "C" void kernel_launch(void* const* d_in, const int* in_sizes, int n_in,
                              void* d_out, int out_size, void* d_ws, size_t ws_size,
                              hipStream_t stream) {
    const float* x      = (const float*)d_in[0];
    const int*   eidx   = (const int*)d_in[1];
    const float* W1     = (const float*)d_in[2];
    const float* a1_src = (const float*)d_in[3];
    const float* a1_dst = (const float*)d_in[4];
    const float* b1     = (const float*)d_in[5];
    const float* W2     = (const float*)d_in[6];
    const float* a2_src = (const float*)d_in[7];
    const float* a2_dst = (const float*)d_in[8];
    const float* b2     = (const float*)d_in[9];
    const float* W3     = (const float*)d_in[10];
    const float* a3_src = (const float*)d_in[11];
    const float* a3_dst = (const float*)d_in[12];
    const float* b3     = (const float*)d_in[13];
    float* out = (float*)d_out;

    const int N = in_sizes[0] / 64;      // 50000
    const int E = in_sizes[1] / 2;       // 800000
    const int NB = (N + 1023) / 1024;

    // ---- workspace layout: ints first, then small floats, then aligned float arena ----
    int* rowptr = (int*)d_ws;                  // N+1
    int* deg    = rowptr + (N + 1);            // N
    int* cursor = deg + N;                     // N
    int* csr    = cursor + N;                  // E
    int* flag   = csr + E;                     // 1
    int* bsum   = flag + 1;                    // NB
    int* boff   = bsum + NB;                   // NB
    uintptr_t pa = (uintptr_t)(boff + NB);
    pa = (pa + 255) & ~(uintptr_t)255;
    float* als  = (float*)pa;                  // N*4
    float* ald  = als + (size_t)N * 4;         // N*4
    float* ps   = ald + (size_t)N * 4;         // 512
    float* pd   = ps + 512;                    // 512
    float* Wstk = pd + 512;                    // 512*64
    uintptr_t pf = (uintptr_t)(Wstk + 512 * 64);
    pf = (pf + 255) & ~(uintptr_t)255;
    float* F    = (float*)pf;

    size_t base_bytes = (pf - (uintptr_t)d_ws);
    bool full = ws_size >= base_bytes + (size_t)N * 640 * sizeof(float);

    // ---- CSR build (shared by all layers) ----
    detect_kernel<<<1, 64, 0, stream>>>(eidx, flag);
    hipMemsetAsync(deg, 0, (size_t)N * sizeof(int), stream);
    deg_kernel<<<(E + 255) / 256, 256, 0, stream>>>(eidx, flag, deg, E, N);
    reduce_kernel<<<NB, 256, 0, stream>>>(deg, bsum, N);
    scan_bsum_kernel<<<1, 64, 0, stream>>>(bsum, boff, NB, rowptr + N);
    block_scan_kernel<<<NB, 256, 0, stream>>>(deg, boff, rowptr, cursor, N);
    scatter_kernel<<<(E + 255) / 256, 256, 0, stream>>>(eidx, flag, cursor, csr, E, N);

    const int alBlocks  = (N * HEADS + 255) / 256;
    const int aggBlocks = (N + 3) / 4;
    const int rowB128   = (N + 127) / 128;

    if (full) {
        float* agg1 = F;                        // [N,256]
        float* out1 = F + (size_t)N * 256;      // [N,256]
        float* h2   = F;                        // [N,128] (agg1 dead)
        float* out2 = F + (size_t)N * 512;      // [N,128]
        float* agg3 = F;                        // [N,512] (h2/out1 dead)

        // layer 1: pre-aggregate x, then per-head GEMM with W1
        proj_kernel<<<1, 256, 0, stream>>>(W1, a1_src, a1_dst, ps, pd, 64, 256, 64);
        alx_kernel<64><<<alBlocks, 256, 0, stream>>>(x, ps, pd, als, ald, N);
        preagg_kernel<64><<<aggBlocks, 256, 0, stream>>>(x, als, ald, rowptr, csr, agg1, N);
        gemm64_kernel<<<dim3(4, rowB128), 256, 0, stream>>>(agg1, 256, 1, W1, 256, out1, 256, b1, N, 64);

        // layer 2: standard (h2 is the narrow side)
        gemm64_kernel<<<dim3(2, rowB128), 256, 0, stream>>>(out1, 256, 0, W2, 128, h2, 128, nullptr, N, 256);
        al_kernel<32><<<alBlocks, 256, 0, stream>>>(h2, a2_src, a2_dst, als, ald, N);
        aggregate_kernel<32, false><<<aggBlocks, 256, 0, stream>>>(h2, als, ald, rowptr, csr, b2, out2, N);

        // layer 3: pre-aggregate x3, stacked GEMM with head-mean folded into Wstk
        proj_kernel<<<2, 256, 0, stream>>>(W3, a3_src, a3_dst, ps, pd, 128, 256, 64);
        alx_kernel<128><<<alBlocks, 256, 0, stream>>>(out2, ps, pd, als, ald, N);
        wstk_kernel<<<128, 256, 0, stream>>>(W3, Wstk);
        preagg_kernel<128><<<aggBlocks, 256, 0, stream>>>(out2, als, ald, rowptr, csr, agg3, N);
        gemm64_kernel<<<dim3(1, rowB128), 256, 0, stream>>>(agg3, 512, 0, Wstk, 64, out, 64, b3, N, 512);
    } else {
        float* out1 = F;                        // [N,256]
        float* agg1 = F + (size_t)N * 256;      // [N,256]
        float* h2   = F + (size_t)N * 256;      // [N,128] (agg1 dead)
        float* out2 = F + (size_t)N * 384;      // [N,128]
        float* h3   = F;                        // [N,256] (out1 dead)

        proj_kernel<<<1, 256, 0, stream>>>(W1, a1_src, a1_dst, ps, pd, 64, 256, 64);
        alx_kernel<64><<<alBlocks, 256, 0, stream>>>(x, ps, pd, als, ald, N);
        preagg_kernel<64><<<aggBlocks, 256, 0, stream>>>(x, als, ald, rowptr, csr, agg1, N);
        gemm64_kernel<<<dim3(4, rowB128), 256, 0, stream>>>(agg1, 256, 1, W1, 256, out1, 256, b1, N, 64);

        gemm64_kernel<<<dim3(2, rowB128), 256, 0, stream>>>(out1, 256, 0, W2, 128, h2, 128, nullptr, N, 256);
        al_kernel<32><<<alBlocks, 256, 0, stream>>>(h2, a2_src, a2_dst, als, ald, N);
        aggregate_kernel<32, false><<<aggBlocks, 256, 0, stream>>>(h2, als, ald, rowptr, csr, b2, out2, N);

        gemm64_kernel<<<dim3(4, rowB128), 256, 0, stream>>>(out2, 128, 0, W3, 256, h3, 256, nullptr, N, 128);
        al_kernel<64><<<alBlocks, 256, 0, stream>>>(h3, a3_src, a3_dst, als, ald, N);
        aggregate_kernel<64, true><<<aggBlocks, 256, 0, stream>>>(h3, als, ald, rowptr, csr, b3, out, N);
    }
}

// Round 8
// 557.261 us; speedup vs baseline: 1.5013x; 1.1100x over previous
//
#include <hip/hip_runtime.h>
#include <hip/hip_bf16.h>

#define HEADS 4

// ---------------- bf16 helpers (bit-level, no struct layout assumptions) ----------------
__device__ __forceinline__ float u2f(unsigned short u) {
    return __uint_as_float(((unsigned)u) << 16);
}
__device__ __forceinline__ unsigned short rne(float v) {
    unsigned b = __float_as_uint(v);
    return (unsigned short)((b + 0x7FFF + ((b >> 16) & 1)) >> 16);
}
__device__ __forceinline__ float ld1(const float* p) { return *p; }
__device__ __forceinline__ float ld1(const __hip_bfloat16* p) {
    return u2f(*reinterpret_cast<const unsigned short*>(p));
}
__device__ __forceinline__ float2 ld2(const float* p) { return *reinterpret_cast<const float2*>(p); }
__device__ __forceinline__ float2 ld2(const __hip_bfloat16* p) {
    ushort2 u = *reinterpret_cast<const ushort2*>(p);
    return make_float2(u2f(u.x), u2f(u.y));
}
__device__ __forceinline__ float4 ld4(const float* p) { return *reinterpret_cast<const float4*>(p); }
__device__ __forceinline__ float4 ld4(const __hip_bfloat16* p) {
    ushort4 u = *reinterpret_cast<const ushort4*>(p);
    return make_float4(u2f(u.x), u2f(u.y), u2f(u.z), u2f(u.w));
}
__device__ __forceinline__ void st1(float* p, float v) { *p = v; }
__device__ __forceinline__ void st1(__hip_bfloat16* p, float v) {
    *reinterpret_cast<unsigned short*>(p) = rne(v);
}
__device__ __forceinline__ void st2(float* p, float a, float b) {
    *reinterpret_cast<float2*>(p) = make_float2(a, b);
}
__device__ __forceinline__ void st2(__hip_bfloat16* p, float a, float b) {
    *reinterpret_cast<ushort2*>(p) = make_ushort2(rne(a), rne(b));
}
__device__ __forceinline__ void st4(float* p, float4 v) { *reinterpret_cast<float4*>(p) = v; }
__device__ __forceinline__ void st4(__hip_bfloat16* p, float4 v) {
    *reinterpret_cast<ushort4*>(p) = make_ushort4(rne(v.x), rne(v.y), rne(v.z), rne(v.w));
}

// ---------------- edge dtype detection ----------------
__global__ void detect_kernel(const int* __restrict__ eidx, int* __restrict__ flag) {
    if (blockIdx.x == 0 && threadIdx.x == 0) {
        int orv = 0;
        for (int i = 0; i < 256; ++i) orv |= eidx[2 * i + 1];
        *flag = (orv == 0) ? 1 : 0;
    }
}
__device__ __forceinline__ int edge_elem(const int* e, size_t idx, int is64) {
    return is64 ? e[2 * idx] : e[idx];
}

// ---------------- CSR build ----------------
__global__ void deg_kernel(const int* __restrict__ eidx, const int* __restrict__ flag,
                           int* __restrict__ deg, int E, int N) {
    int e = blockIdx.x * blockDim.x + threadIdx.x;
    if (e < E) {
        int is64 = *flag;
        int d = edge_elem(eidx, (size_t)E + e, is64);
        if ((unsigned)d < (unsigned)N) atomicAdd(&deg[d], 1);
    }
}

__global__ void reduce_kernel(const int* __restrict__ deg, int* __restrict__ bsum, int n) {
    __shared__ int sdata[256];
    int base = blockIdx.x * 1024;
    int t = threadIdx.x;
    int v = 0;
#pragma unroll
    for (int j = 0; j < 4; ++j) {
        int i = base + t + j * 256;
        if (i < n) v += deg[i];
    }
    sdata[t] = v;
    __syncthreads();
    for (int off = 128; off > 0; off >>= 1) {
        if (t < off) sdata[t] += sdata[t + off];
        __syncthreads();
    }
    if (t == 0) bsum[blockIdx.x] = sdata[0];
}

__global__ void scan_bsum_kernel(const int* __restrict__ bsum, int* __restrict__ boff,
                                 int nb, int* __restrict__ totalp) {
    int lane = threadIdx.x;
    int carry = 0;
    for (int base = 0; base < nb; base += 64) {
        int i = base + lane;
        int v = (i < nb) ? bsum[i] : 0;
        int inc = v;
        for (int off = 1; off < 64; off <<= 1) {
            int tt = __shfl_up(inc, off);
            if (lane >= off) inc += tt;
        }
        if (i < nb) boff[i] = carry + inc - v;
        carry += __shfl(inc, 63);
    }
    if (lane == 0) *totalp = carry;
}

__global__ void block_scan_kernel(const int* __restrict__ deg, const int* __restrict__ boff,
                                  int* __restrict__ rowptr, int* __restrict__ cursor, int n) {
    __shared__ int wsum[4];
    int base = blockIdx.x * 1024;
    int t = threadIdx.x;
    int lane = t & 63, w = t >> 6;
    int v[4];
    int lsum = 0;
#pragma unroll
    for (int j = 0; j < 4; ++j) {
        int i = base + t * 4 + j;
        v[j] = (i < n) ? deg[i] : 0;
        lsum += v[j];
    }
    int inc = lsum;
    for (int off = 1; off < 64; off <<= 1) {
        int tt = __shfl_up(inc, off);
        if (lane >= off) inc += tt;
    }
    if (lane == 63) wsum[w] = inc;
    __syncthreads();
    int woff = 0;
    for (int i = 0; i < w; ++i) woff += wsum[i];
    int ex = boff[blockIdx.x] + woff + inc - lsum;
#pragma unroll
    for (int j = 0; j < 4; ++j) {
        int i = base + t * 4 + j;
        if (i < n) { rowptr[i] = ex; cursor[i] = ex; }
        ex += v[j];
    }
}

__global__ void scatter_kernel(const int* __restrict__ eidx, const int* __restrict__ flag,
                               int* __restrict__ cursor, int* __restrict__ csr_src, int E, int N) {
    int e = blockIdx.x * blockDim.x + threadIdx.x;
    if (e < E) {
        int is64 = *flag;
        int s = edge_elem(eidx, (size_t)e, is64);
        int d = edge_elem(eidx, (size_t)E + e, is64);
        if ((unsigned)d < (unsigned)N && (unsigned)s < (unsigned)N) {
            int pos = atomicAdd(&cursor[d], 1);
            csr_src[pos] = s;
        }
    }
}

// ---------------- f32 -> bf16 convert ----------------
__global__ void f2b_kernel(const float* __restrict__ src, __hip_bfloat16* __restrict__ dst, int n8) {
    int i = blockIdx.x * blockDim.x + threadIdx.x;
    if (i < n8) {
        float4 a = *reinterpret_cast<const float4*>(&src[i * 8]);
        float4 b = *reinterpret_cast<const float4*>(&src[i * 8 + 4]);
        st4(&dst[i * 8], a);
        st4(&dst[i * 8 + 4], b);
    }
}

// ---------------- projected attention vectors ----------------
__global__ void proj_kernel(const float* __restrict__ W, const float* __restrict__ as,
                            const float* __restrict__ ad, float* __restrict__ ps,
                            float* __restrict__ pd, int K, int M, int Ch) {
    int idx = blockIdx.x * blockDim.x + threadIdx.x;
    if (idx >= 4 * K) return;
    int h = idx / K, k = idx % K;
    float ss = 0.f, sd = 0.f;
    for (int c = 0; c < Ch; ++c) {
        float w = W[(size_t)k * M + h * Ch + c];
        ss += w * as[h * Ch + c];
        sd += w * ad[h * Ch + c];
    }
    ps[idx] = ss;
    pd[idx] = sd;
}

// ---------------- logits from raw features ----------------
template <int K, typename T>
__global__ void alx_kernel(const T* __restrict__ x, const float* __restrict__ ps,
                           const float* __restrict__ pd, float* __restrict__ als,
                           float* __restrict__ ald, int N) {
    int idx = blockIdx.x * blockDim.x + threadIdx.x;
    if (idx >= N * 4) return;
    int n = idx >> 2, h = idx & 3;
    const T* row = x + (size_t)n * K;
    const float* vs = ps + h * K;
    const float* vd = pd + h * K;
    float ss = 0.f, sd = 0.f;
#pragma unroll
    for (int c = 0; c < K; c += 4) {
        float4 v = ld4(&row[c]);
        float4 a = *reinterpret_cast<const float4*>(&vs[c]);
        float4 b = *reinterpret_cast<const float4*>(&vd[c]);
        ss += v.x * a.x + v.y * a.y + v.z * a.z + v.w * a.w;
        sd += v.x * b.x + v.y * b.y + v.z * b.z + v.w * b.w;
    }
    als[idx] = ss;
    ald[idx] = sd;
}

// ---------------- logits from interleaved head features ----------------
template <int C, typename T>
__global__ void al_kernel(const T* __restrict__ h,
                          const float* __restrict__ a_src, const float* __restrict__ a_dst,
                          float* __restrict__ al_s, float* __restrict__ al_d, int N) {
    int idx = blockIdx.x * blockDim.x + threadIdx.x;
    if (idx >= N * HEADS) return;
    int n = idx >> 2, hd = idx & 3;
    const T* row = h + (size_t)n * HEADS * C + hd * C;
    float ss = 0.f, sd = 0.f;
#pragma unroll
    for (int c = 0; c < C; c += 4) {
        float4 v = ld4(&row[c]);
        float4 as = *reinterpret_cast<const float4*>(&a_src[hd * C + c]);
        float4 ad = *reinterpret_cast<const float4*>(&a_dst[hd * C + c]);
        ss += v.x * as.x + v.y * as.y + v.z * as.z + v.w * as.w;
        sd += v.x * ad.x + v.y * ad.y + v.z * ad.z + v.w * ad.w;
    }
    al_s[idx] = ss;
    al_d[idx] = sd;
}

// ---------------- per-edge softmax weights: wgt[k*4+h] = exp(lrelu(als[src]+ald[dst])) ----------------
__global__ void ew_kernel(const float* __restrict__ als, const float* __restrict__ ald,
                          const int* __restrict__ rowptr, const int* __restrict__ csr,
                          float* __restrict__ wgt, int N) {
    int wave = (blockIdx.x * blockDim.x + threadIdx.x) >> 6;
    int lane = threadIdx.x & 63;
    if (wave >= N) return;
    int h = lane & 3, eo = lane >> 2;  // 16 edges/pass, 4 heads
    float aldv = ald[wave * 4 + h];
    int beg = rowptr[wave], end = rowptr[wave + 1];
    for (int k = beg + eo; k < end; k += 16) {
        int j = csr[k];
        float e = als[j * 4 + h] + aldv;
        e = fmaxf(e, 0.2f * e);
        wgt[(size_t)k * 4 + h] = __expf(e);
    }
}

// ---------------- pre-aggregation (wave per node), precomputed weights ----------------
template <int K, typename TIN, typename TOUT>
__global__ void preagg_kernel(const TIN* __restrict__ x, const float* __restrict__ wgt,
                              const int* __restrict__ rowptr, const int* __restrict__ csr,
                              TOUT* __restrict__ agg, int N) {
    constexpr int V = K / 64;  // 1 or 2
    int wave = (blockIdx.x * blockDim.x + threadIdx.x) >> 6;
    int lane = threadIdx.x & 63;
    if (wave >= N) return;
    float s0 = 0.f, s1 = 0.f, s2 = 0.f, s3 = 0.f;
    float acc[4][V] = {};
    int beg = rowptr[wave], end = rowptr[wave + 1];
    int k = beg;
    for (; k + 2 <= end; k += 2) {
        int j0 = csr[k], j1 = csr[k + 1];
        float4 w0 = *reinterpret_cast<const float4*>(&wgt[(size_t)k * 4]);
        float4 w1 = *reinterpret_cast<const float4*>(&wgt[(size_t)(k + 1) * 4]);
        s0 += w0.x + w1.x; s1 += w0.y + w1.y; s2 += w0.z + w1.z; s3 += w0.w + w1.w;
        if (V == 1) {
            float v0 = ld1(&x[(size_t)j0 * K + lane]);
            float v1 = ld1(&x[(size_t)j1 * K + lane]);
            acc[0][0] += w0.x * v0 + w1.x * v1;
            acc[1][0] += w0.y * v0 + w1.y * v1;
            acc[2][0] += w0.z * v0 + w1.z * v1;
            acc[3][0] += w0.w * v0 + w1.w * v1;
        } else {
            float2 v0 = ld2(&x[(size_t)j0 * K + lane * 2]);
            float2 v1 = ld2(&x[(size_t)j1 * K + lane * 2]);
            acc[0][0] += w0.x * v0.x + w1.x * v1.x; acc[0][1] += w0.x * v0.y + w1.x * v1.y;
            acc[1][0] += w0.y * v0.x + w1.y * v1.x; acc[1][1] += w0.y * v0.y + w1.y * v1.y;
            acc[2][0] += w0.z * v0.x + w1.z * v1.x; acc[2][1] += w0.z * v0.y + w1.z * v1.y;
            acc[3][0] += w0.w * v0.x + w1.w * v1.x; acc[3][1] += w0.w * v0.y + w1.w * v1.y;
        }
    }
    if (k < end) {
        int j0 = csr[k];
        float4 w0 = *reinterpret_cast<const float4*>(&wgt[(size_t)k * 4]);
        s0 += w0.x; s1 += w0.y; s2 += w0.z; s3 += w0.w;
        if (V == 1) {
            float v0 = ld1(&x[(size_t)j0 * K + lane]);
            acc[0][0] += w0.x * v0; acc[1][0] += w0.y * v0;
            acc[2][0] += w0.z * v0; acc[3][0] += w0.w * v0;
        } else {
            float2 v0 = ld2(&x[(size_t)j0 * K + lane * 2]);
            acc[0][0] += w0.x * v0.x; acc[0][1] += w0.x * v0.y;
            acc[1][0] += w0.y * v0.x; acc[1][1] += w0.y * v0.y;
            acc[2][0] += w0.z * v0.x; acc[2][1] += w0.z * v0.y;
            acc[3][0] += w0.w * v0.x; acc[3][1] += w0.w * v0.y;
        }
    }
    float inv[4] = {1.f / (s0 + 1e-16f), 1.f / (s1 + 1e-16f),
                    1.f / (s2 + 1e-16f), 1.f / (s3 + 1e-16f)};
    size_t o = (size_t)wave * 4 * K;
#pragma unroll
    for (int h = 0; h < 4; ++h) {
        if (V == 1) {
            st1(&agg[o + h * K + lane], acc[h][0] * inv[h]);
        } else {
            st2(&agg[o + h * K + lane * 2], acc[h][0] * inv[h], acc[h][1] * inv[h]);
        }
    }
}

// ---------------- post-GEMM aggregation, interleaved heads, precomputed weights ----------------
template <int C, typename TIN, typename TOUT>
__global__ void aggregate_kernel(const TIN* __restrict__ h, const float* __restrict__ wgt,
                                 const int* __restrict__ rowptr, const int* __restrict__ csr,
                                 const float* __restrict__ bias, TOUT* __restrict__ outp, int N) {
    constexpr int VPT = 4 * C / 64;  // 2 for C=32
    int wave = (blockIdx.x * blockDim.x + threadIdx.x) >> 6;
    int lane = threadIdx.x & 63;
    if (wave >= N) return;
    int head = lane >> 4;
    int c0 = (lane & 15) * VPT;
    const TIN* hb = h + head * C + c0;

    float s = 0.f;
    float acc[VPT] = {};
    int beg = rowptr[wave], end = rowptr[wave + 1];
    int k = beg;
    for (; k + 2 <= end; k += 2) {
        int j0 = csr[k], j1 = csr[k + 1];
        float w0 = wgt[(size_t)k * 4 + head];
        float w1 = wgt[(size_t)(k + 1) * 4 + head];
        s += w0 + w1;
        if (VPT == 4) {
            float4 v0 = ld4(hb + (size_t)j0 * (4 * C));
            float4 v1 = ld4(hb + (size_t)j1 * (4 * C));
            acc[0] += w0 * v0.x + w1 * v1.x; acc[1] += w0 * v0.y + w1 * v1.y;
            acc[2] += w0 * v0.z + w1 * v1.z; acc[3] += w0 * v0.w + w1 * v1.w;
        } else {
            float2 v0 = ld2(hb + (size_t)j0 * (4 * C));
            float2 v1 = ld2(hb + (size_t)j1 * (4 * C));
            acc[0] += w0 * v0.x + w1 * v1.x; acc[1] += w0 * v0.y + w1 * v1.y;
        }
    }
    if (k < end) {
        int j0 = csr[k];
        float w0 = wgt[(size_t)k * 4 + head];
        s += w0;
        if (VPT == 4) {
            float4 v0 = ld4(hb + (size_t)j0 * (4 * C));
            acc[0] += w0 * v0.x; acc[1] += w0 * v0.y; acc[2] += w0 * v0.z; acc[3] += w0 * v0.w;
        } else {
            float2 v0 = ld2(hb + (size_t)j0 * (4 * C));
            acc[0] += w0 * v0.x; acc[1] += w0 * v0.y;
        }
    }
    float inv = 1.f / (s + 1e-16f);
    size_t o = (size_t)wave * (4 * C) + head * C + c0;
    if (VPT == 2) {
        st2(&outp[o], acc[0] * inv + bias[head * C + c0],
                      acc[1] * inv + bias[head * C + c0 + 1]);
    } else {
#pragma unroll
        for (int j = 0; j < VPT; ++j)
            st1(&outp[o + j], acc[j] * inv + bias[head * C + c0 + j]);
    }
}

// ---------------- fallback: inline-exp aggregation (f32, MEAN option) ----------------
template <int C, bool MEAN>
__global__ void aggregate_f32_kernel(const float* __restrict__ h,
                                     const float* __restrict__ al_s, const float* __restrict__ al_d,
                                     const int* __restrict__ rowptr, const int* __restrict__ csr_src,
                                     const float* __restrict__ bias,
                                     float* __restrict__ outf, int N) {
    constexpr int VPT = 4 * C / 64;
    int wave = (blockIdx.x * blockDim.x + threadIdx.x) >> 6;
    int lane = threadIdx.x & 63;
    if (wave >= N) return;
    int head = lane >> 4;
    int c0 = (lane & 15) * VPT;
    const float* hb = h + head * C + c0;
    float ald = al_d[wave * HEADS + head];
    float s = 0.f;
    float acc[VPT] = {};
    int beg = rowptr[wave], end = rowptr[wave + 1];
    for (int k = beg; k < end; ++k) {
        int s0 = csr_src[k];
        float e0 = al_s[s0 * HEADS + head] + ald;
        e0 = fmaxf(e0, 0.2f * e0);
        float w0 = __expf(e0);
        s += w0;
        const float* p0 = hb + (size_t)s0 * (HEADS * C);
#pragma unroll
        for (int j = 0; j < VPT; ++j) acc[j] += w0 * p0[j];
    }
    float inv = 1.f / (s + 1e-16f);
    if (!MEAN) {
        size_t o = (size_t)wave * (HEADS * C) + head * C + c0;
#pragma unroll
        for (int j = 0; j < VPT; ++j)
            outf[o + j] = acc[j] * inv + bias[head * C + c0 + j];
    } else {
        float v[VPT];
#pragma unroll
        for (int j = 0; j < VPT; ++j) {
            float t = acc[j] * inv;
            t += __shfl_xor(t, 16);
            t += __shfl_xor(t, 32);
            v[j] = t * 0.25f + bias[c0 + j];
        }
        if (lane < 16) {
#pragma unroll
            for (int j = 0; j < VPT; ++j)
                outf[(size_t)wave * C + c0 + j] = v[j];
        }
    }
}

// ---------------- W3 restack with head-mean folded ----------------
__global__ void wstk_kernel(const float* __restrict__ W3, float* __restrict__ Wstk) {
    int idx = blockIdx.x * blockDim.x + threadIdx.x;
    if (idx >= 512 * 64) return;
    int c = idx & 63;
    int hk = idx >> 6;
    int h = hk >> 7, k = hk & 127;
    Wstk[idx] = W3[(size_t)k * 256 + h * 64 + c] * 0.25f;
}

// ---------------- GEMM: O[N, col0..+63] = A[N, aOff..+K) @ B, BM=128 BN=64 ----------------
template <typename TA, typename TOUT>
__global__ __launch_bounds__(256) void gemm64_kernel(const TA* __restrict__ A, int lda, int aSel,
                                                     const float* __restrict__ B, int ldb,
                                                     TOUT* __restrict__ O, int ldo,
                                                     const float* __restrict__ bias,
                                                     int N, int K) {
    __shared__ float As[16][132];
    __shared__ float Bs[16][68];
    int col0 = blockIdx.x * 64;
    int row0 = blockIdx.y * 128;
    int aOff = aSel ? col0 : 0;
    int tid = threadIdx.x;
    int tx = tid & 15, ty = tid >> 4;
    float acc[8][4] = {};
    for (int k0 = 0; k0 < K; k0 += 16) {
        for (int i = tid; i < 512; i += 256) {
            int r = i >> 2, kc = (i & 3) * 4;
            int gr = row0 + r;
            float4 v = make_float4(0.f, 0.f, 0.f, 0.f);
            if (gr < N) v = ld4(&A[(size_t)gr * lda + aOff + k0 + kc]);
            As[kc + 0][r] = v.x; As[kc + 1][r] = v.y;
            As[kc + 2][r] = v.z; As[kc + 3][r] = v.w;
        }
        {
            int k = tid >> 4, c4 = (tid & 15) * 4;
            float4 v = *reinterpret_cast<const float4*>(&B[(size_t)(k0 + k) * ldb + col0 + c4]);
            *reinterpret_cast<float4*>(&Bs[k][c4]) = v;
        }
        __syncthreads();
#pragma unroll
        for (int k = 0; k < 16; ++k) {
            float4 a0 = *reinterpret_cast<const float4*>(&As[k][ty * 8]);
            float4 a1 = *reinterpret_cast<const float4*>(&As[k][ty * 8 + 4]);
            float4 b0 = *reinterpret_cast<const float4*>(&Bs[k][tx * 4]);
            float ar[8] = {a0.x, a0.y, a0.z, a0.w, a1.x, a1.y, a1.z, a1.w};
            float br[4] = {b0.x, b0.y, b0.z, b0.w};
#pragma unroll
            for (int i = 0; i < 8; ++i)
#pragma unroll
                for (int j = 0; j < 4; ++j) acc[i][j] += ar[i] * br[j];
        }
        __syncthreads();
    }
    float4 bv = make_float4(0.f, 0.f, 0.f, 0.f);
    if (bias) bv = *reinterpret_cast<const float4*>(&bias[col0 + tx * 4]);
#pragma unroll
    for (int i = 0; i < 8; ++i) {
        int r = row0 + ty * 8 + i;
        if (r < N) {
            float4 v = make_float4(acc[i][0] + bv.x, acc[i][1] + bv.y,
                                   acc[i][2] + bv.z, acc[i][3] + bv.w);
            st4(&O[(size_t)r * ldo + col0 + tx * 4], v);
        }
    }
}

// ---------------- launch ----------------
extern "C" void kernel_launch(void* const* d_in, const int* in_sizes, int n_in,
                              void* d_out, int out_size, void* d_ws, size_t ws_size,
                              hipStream_t stream) {
    const float* x      = (const float*)d_in[0];
    const int*   eidx   = (const int*)d_in[1];
    const float* W1     = (const float*)d_in[2];
    const float* a1_src = (const float*)d_in[3];
    const float* a1_dst = (const float*)d_in[4];
    const float* b1     = (const float*)d_in[5];
    const float* W2     = (const float*)d_in[6];
    const float* a2_src = (const float*)d_in[7];
    const float* a2_dst = (const float*)d_in[8];
    const float* b2     = (const float*)d_in[9];
    const float* W3     = (const float*)d_in[10];
    const float* a3_src = (const float*)d_in[11];
    const float* a3_dst = (const float*)d_in[12];
    const float* b3     = (const float*)d_in[13];
    float* out = (float*)d_out;

    const int N = in_sizes[0] / 64;      // 50000
    const int E = in_sizes[1] / 2;       // 800000
    const int NB = (N + 1023) / 1024;

    // ---- workspace: ints, small floats, then aligned arena F of N*640 floats ----
    int* rowptr = (int*)d_ws;
    int* deg    = rowptr + (N + 1);
    int* cursor = deg + N;
    int* csr    = cursor + N;
    int* flag   = csr + E;
    int* bsum   = flag + 1;
    int* boff   = bsum + NB;
    uintptr_t pa = (uintptr_t)(boff + NB);
    pa = (pa + 255) & ~(uintptr_t)255;
    float* als  = (float*)pa;                  // N*4
    float* ald  = als + (size_t)N * 4;         // N*4
    float* ps   = ald + (size_t)N * 4;         // 512
    float* pd   = ps + 512;                    // 512
    float* Wstk = pd + 512;                    // 512*64
    uintptr_t pf = (uintptr_t)(Wstk + 512 * 64);
    pf = (pf + 255) & ~(uintptr_t)255;
    float* F    = (float*)pf;

    size_t base_bytes = (pf - (uintptr_t)d_ws);
    bool full = ws_size >= base_bytes + (size_t)N * 640 * sizeof(float);

    // ---- CSR build ----
    detect_kernel<<<1, 64, 0, stream>>>(eidx, flag);
    hipMemsetAsync(deg, 0, (size_t)N * sizeof(int), stream);
    deg_kernel<<<(E + 255) / 256, 256, 0, stream>>>(eidx, flag, deg, E, N);
    reduce_kernel<<<NB, 256, 0, stream>>>(deg, bsum, N);
    scan_bsum_kernel<<<1, 64, 0, stream>>>(bsum, boff, NB, rowptr + N);
    block_scan_kernel<<<NB, 256, 0, stream>>>(deg, boff, rowptr, cursor, N);
    scatter_kernel<<<(E + 255) / 256, 256, 0, stream>>>(eidx, flag, cursor, csr, E, N);

    const int alBlocks  = (N * HEADS + 255) / 256;
    const int aggBlocks = (N + 3) / 4;
    const int rowB128   = (N + 127) / 128;

    if (full) {
        // arena plan (float units):
        //   agg1 f32 [0,256N) | out1 f32 [256N,512N) | xb bf16 [512N,544N)
        //   wgt f32 [544N,608N) | h2b bf16 [0,64N) | out2b bf16 [64N,128N)
        //   agg3 bf16 [128N,384N)
        float* agg1 = F;
        float* out1 = F + (size_t)N * 256;
        __hip_bfloat16* xb    = (__hip_bfloat16*)(F + (size_t)N * 512);
        float*          wgt   = F + (size_t)N * 544;
        __hip_bfloat16* h2b   = (__hip_bfloat16*)F;
        __hip_bfloat16* out2b = (__hip_bfloat16*)(F + (size_t)N * 64);
        __hip_bfloat16* agg3  = (__hip_bfloat16*)(F + (size_t)N * 128);

        // layer 1
        f2b_kernel<<<(N * 64 / 8 + 255) / 256, 256, 0, stream>>>(x, xb, N * 64 / 8);
        proj_kernel<<<1, 256, 0, stream>>>(W1, a1_src, a1_dst, ps, pd, 64, 256, 64);
        alx_kernel<64, float><<<alBlocks, 256, 0, stream>>>(x, ps, pd, als, ald, N);
        ew_kernel<<<aggBlocks, 256, 0, stream>>>(als, ald, rowptr, csr, wgt, N);
        preagg_kernel<64, __hip_bfloat16, float><<<aggBlocks, 256, 0, stream>>>(xb, wgt, rowptr, csr, agg1, N);
        gemm64_kernel<float, float><<<dim3(4, rowB128), 256, 0, stream>>>(agg1, 256, 1, W1, 256, out1, 256, b1, N, 64);

        // layer 2
        gemm64_kernel<float, __hip_bfloat16><<<dim3(2, rowB128), 256, 0, stream>>>(out1, 256, 0, W2, 128, h2b, 128, nullptr, N, 256);
        al_kernel<32, __hip_bfloat16><<<alBlocks, 256, 0, stream>>>(h2b, a2_src, a2_dst, als, ald, N);
        ew_kernel<<<aggBlocks, 256, 0, stream>>>(als, ald, rowptr, csr, wgt, N);
        aggregate_kernel<32, __hip_bfloat16, __hip_bfloat16><<<aggBlocks, 256, 0, stream>>>(h2b, wgt, rowptr, csr, b2, out2b, N);

        // layer 3
        proj_kernel<<<2, 256, 0, stream>>>(W3, a3_src, a3_dst, ps, pd, 128, 256, 64);
        wstk_kernel<<<128, 256, 0, stream>>>(W3, Wstk);
        alx_kernel<128, __hip_bfloat16><<<alBlocks, 256, 0, stream>>>(out2b, ps, pd, als, ald, N);
        ew_kernel<<<aggBlocks, 256, 0, stream>>>(als, ald, rowptr, csr, wgt, N);
        preagg_kernel<128, __hip_bfloat16, __hip_bfloat16><<<aggBlocks, 256, 0, stream>>>(out2b, wgt, rowptr, csr, agg3, N);
        gemm64_kernel<__hip_bfloat16, float><<<dim3(1, rowB128), 256, 0, stream>>>(agg3, 512, 0, Wstk, 64, out, 64, b3, N, 512);
    } else {
        // fallback: all-f32 path within N*512-float arena
        float* out1 = F;                        // [N,256]
        float* h2   = F + (size_t)N * 256;      // [N,128]
        float* out2 = F + (size_t)N * 384;      // [N,128]
        float* h3   = F;                        // [N,256] (out1 dead)

        gemm64_kernel<float, float><<<dim3(4, rowB128), 256, 0, stream>>>(x, 64, 0, W1, 256, out1, 256, nullptr, N, 64);
        // (x@W1 without pre-agg; then aggregate post-GEMM)
        al_kernel<64, float><<<alBlocks, 256, 0, stream>>>(out1, a1_src, a1_dst, als, ald, N);
        aggregate_f32_kernel<64, false><<<aggBlocks, 256, 0, stream>>>(out1, als, ald, rowptr, csr, b1, h3, N);
        // NOTE: h3 == out1 region would alias; use h2/out2 region as temp for L1 output instead
        // (fallback is defensive only; full path is the measured one)
        gemm64_kernel<float, float><<<dim3(2, rowB128), 256, 0, stream>>>(h3, 256, 0, W2, 128, h2, 128, nullptr, N, 256);
        al_kernel<32, float><<<alBlocks, 256, 0, stream>>>(h2, a2_src, a2_dst, als, ald, N);
        aggregate_f32_kernel<32, false><<<aggBlocks, 256, 0, stream>>>(h2, als, ald, rowptr, csr, b2, out2, N);
        gemm64_kernel<float, float><<<dim3(4, rowB128), 256, 0, stream>>>(out2, 128, 0, W3, 256, h3, 256, nullptr, N, 128);
        al_kernel<64, float><<<alBlocks, 256, 0, stream>>>(h3, a3_src, a3_dst, als, ald, N);
        aggregate_f32_kernel<64, true><<<aggBlocks, 256, 0, stream>>>(h3, als, ald, rowptr, csr, b3, out, N);
    }
}

// Round 9
// 468.366 us; speedup vs baseline: 1.7863x; 1.1898x over previous
//
#include <hip/hip_runtime.h>
#include <hip/hip_bf16.h>

#define HEADS 4

typedef __attribute__((ext_vector_type(4))) float f32x4;
typedef __attribute__((ext_vector_type(8))) short s16x8;

// ---------------- bf16 helpers ----------------
__device__ __forceinline__ float u2f(unsigned short u) {
    return __uint_as_float(((unsigned)u) << 16);
}
__device__ __forceinline__ unsigned short rne(float v) {
    unsigned b = __float_as_uint(v);
    return (unsigned short)((b + 0x7FFF + ((b >> 16) & 1)) >> 16);
}
__device__ __forceinline__ float ld1(const float* p) { return *p; }
__device__ __forceinline__ float ld1(const __hip_bfloat16* p) {
    return u2f(*reinterpret_cast<const unsigned short*>(p));
}
__device__ __forceinline__ float2 ld2(const float* p) { return *reinterpret_cast<const float2*>(p); }
__device__ __forceinline__ float2 ld2(const __hip_bfloat16* p) {
    ushort2 u = *reinterpret_cast<const ushort2*>(p);
    return make_float2(u2f(u.x), u2f(u.y));
}
__device__ __forceinline__ float4 ld4(const float* p) { return *reinterpret_cast<const float4*>(p); }
__device__ __forceinline__ float4 ld4(const __hip_bfloat16* p) {
    ushort4 u = *reinterpret_cast<const ushort4*>(p);
    return make_float4(u2f(u.x), u2f(u.y), u2f(u.z), u2f(u.w));
}
__device__ __forceinline__ void st1(float* p, float v) { *p = v; }
__device__ __forceinline__ void st1(__hip_bfloat16* p, float v) {
    *reinterpret_cast<unsigned short*>(p) = rne(v);
}
__device__ __forceinline__ void st2(float* p, float a, float b) {
    *reinterpret_cast<float2*>(p) = make_float2(a, b);
}
__device__ __forceinline__ void st2(__hip_bfloat16* p, float a, float b) {
    *reinterpret_cast<ushort2*>(p) = make_ushort2(rne(a), rne(b));
}
__device__ __forceinline__ void st4(float* p, float4 v) { *reinterpret_cast<float4*>(p) = v; }
__device__ __forceinline__ void st4(__hip_bfloat16* p, float4 v) {
    *reinterpret_cast<ushort4*>(p) = make_ushort4(rne(v.x), rne(v.y), rne(v.z), rne(v.w));
}

// ---------------- edge dtype detection ----------------
__global__ void detect_kernel(const int* __restrict__ eidx, int* __restrict__ flag) {
    if (blockIdx.x == 0 && threadIdx.x == 0) {
        int orv = 0;
        for (int i = 0; i < 256; ++i) orv |= eidx[2 * i + 1];
        *flag = (orv == 0) ? 1 : 0;
    }
}
__device__ __forceinline__ int edge_elem(const int* e, size_t idx, int is64) {
    return is64 ? e[2 * idx] : e[idx];
}

// ---------------- CSR build ----------------
__global__ void deg_kernel(const int* __restrict__ eidx, const int* __restrict__ flag,
                           int* __restrict__ deg, int E, int N) {
    int e = blockIdx.x * blockDim.x + threadIdx.x;
    if (e < E) {
        int is64 = *flag;
        int d = edge_elem(eidx, (size_t)E + e, is64);
        if ((unsigned)d < (unsigned)N) atomicAdd(&deg[d], 1);
    }
}

__global__ void reduce_kernel(const int* __restrict__ deg, int* __restrict__ bsum, int n) {
    __shared__ int sdata[256];
    int base = blockIdx.x * 1024;
    int t = threadIdx.x;
    int v = 0;
#pragma unroll
    for (int j = 0; j < 4; ++j) {
        int i = base + t + j * 256;
        if (i < n) v += deg[i];
    }
    sdata[t] = v;
    __syncthreads();
    for (int off = 128; off > 0; off >>= 1) {
        if (t < off) sdata[t] += sdata[t + off];
        __syncthreads();
    }
    if (t == 0) bsum[blockIdx.x] = sdata[0];
}

__global__ void scan_bsum_kernel(const int* __restrict__ bsum, int* __restrict__ boff,
                                 int nb, int* __restrict__ totalp) {
    int lane = threadIdx.x;
    int carry = 0;
    for (int base = 0; base < nb; base += 64) {
        int i = base + lane;
        int v = (i < nb) ? bsum[i] : 0;
        int inc = v;
        for (int off = 1; off < 64; off <<= 1) {
            int tt = __shfl_up(inc, off);
            if (lane >= off) inc += tt;
        }
        if (i < nb) boff[i] = carry + inc - v;
        carry += __shfl(inc, 63);
    }
    if (lane == 0) *totalp = carry;
}

__global__ void block_scan_kernel(const int* __restrict__ deg, const int* __restrict__ boff,
                                  int* __restrict__ rowptr, int* __restrict__ cursor, int n) {
    __shared__ int wsum[4];
    int base = blockIdx.x * 1024;
    int t = threadIdx.x;
    int lane = t & 63, w = t >> 6;
    int v[4];
    int lsum = 0;
#pragma unroll
    for (int j = 0; j < 4; ++j) {
        int i = base + t * 4 + j;
        v[j] = (i < n) ? deg[i] : 0;
        lsum += v[j];
    }
    int inc = lsum;
    for (int off = 1; off < 64; off <<= 1) {
        int tt = __shfl_up(inc, off);
        if (lane >= off) inc += tt;
    }
    if (lane == 63) wsum[w] = inc;
    __syncthreads();
    int woff = 0;
    for (int i = 0; i < w; ++i) woff += wsum[i];
    int ex = boff[blockIdx.x] + woff + inc - lsum;
#pragma unroll
    for (int j = 0; j < 4; ++j) {
        int i = base + t * 4 + j;
        if (i < n) { rowptr[i] = ex; cursor[i] = ex; }
        ex += v[j];
    }
}

__global__ void scatter_kernel(const int* __restrict__ eidx, const int* __restrict__ flag,
                               int* __restrict__ cursor, int* __restrict__ csr_src, int E, int N) {
    int e = blockIdx.x * blockDim.x + threadIdx.x;
    if (e < E) {
        int is64 = *flag;
        int s = edge_elem(eidx, (size_t)e, is64);
        int d = edge_elem(eidx, (size_t)E + e, is64);
        if ((unsigned)d < (unsigned)N && (unsigned)s < (unsigned)N) {
            int pos = atomicAdd(&cursor[d], 1);
            csr_src[pos] = s;
        }
    }
}

// ---------------- f32 -> bf16 convert ----------------
__global__ void f2b_kernel(const float* __restrict__ src, __hip_bfloat16* __restrict__ dst, int n8) {
    int i = blockIdx.x * blockDim.x + threadIdx.x;
    if (i < n8) {
        float4 a = *reinterpret_cast<const float4*>(&src[i * 8]);
        float4 b = *reinterpret_cast<const float4*>(&src[i * 8 + 4]);
        st4(&dst[i * 8], a);
        st4(&dst[i * 8 + 4], b);
    }
}

// ---------------- weight transpose+convert: Bt[m][k] = src[k][m] (bf16) ----------------
__global__ void wtb_kernel(const float* __restrict__ src, __hip_bfloat16* __restrict__ dst,
                           int K, int M) {
    int idx = blockIdx.x * blockDim.x + threadIdx.x;
    if (idx >= K * M) return;
    int k = idx / M, m = idx % M;
    st1(&dst[(size_t)m * K + k], src[idx]);
}

// ---------------- projected attention vectors ----------------
__global__ void proj_kernel(const float* __restrict__ W, const float* __restrict__ as,
                            const float* __restrict__ ad, float* __restrict__ ps,
                            float* __restrict__ pd, int K, int M, int Ch) {
    int idx = blockIdx.x * blockDim.x + threadIdx.x;
    if (idx >= 4 * K) return;
    int h = idx / K, k = idx % K;
    float ss = 0.f, sd = 0.f;
    for (int c = 0; c < Ch; ++c) {
        float w = W[(size_t)k * M + h * Ch + c];
        ss += w * as[h * Ch + c];
        sd += w * ad[h * Ch + c];
    }
    ps[idx] = ss;
    pd[idx] = sd;
}

// ---------------- logits from raw features ----------------
template <int K, typename T>
__global__ void alx_kernel(const T* __restrict__ x, const float* __restrict__ ps,
                           const float* __restrict__ pd, float* __restrict__ als,
                           float* __restrict__ ald, int N) {
    int idx = blockIdx.x * blockDim.x + threadIdx.x;
    if (idx >= N * 4) return;
    int n = idx >> 2, h = idx & 3;
    const T* row = x + (size_t)n * K;
    const float* vs = ps + h * K;
    const float* vd = pd + h * K;
    float ss = 0.f, sd = 0.f;
#pragma unroll
    for (int c = 0; c < K; c += 4) {
        float4 v = ld4(&row[c]);
        float4 a = *reinterpret_cast<const float4*>(&vs[c]);
        float4 b = *reinterpret_cast<const float4*>(&vd[c]);
        ss += v.x * a.x + v.y * a.y + v.z * a.z + v.w * a.w;
        sd += v.x * b.x + v.y * b.y + v.z * b.z + v.w * b.w;
    }
    als[idx] = ss;
    ald[idx] = sd;
}

// ---------------- logits from interleaved head features ----------------
template <int C, typename T>
__global__ void al_kernel(const T* __restrict__ h,
                          const float* __restrict__ a_src, const float* __restrict__ a_dst,
                          float* __restrict__ al_s, float* __restrict__ al_d, int N) {
    int idx = blockIdx.x * blockDim.x + threadIdx.x;
    if (idx >= N * HEADS) return;
    int n = idx >> 2, hd = idx & 3;
    const T* row = h + (size_t)n * HEADS * C + hd * C;
    float ss = 0.f, sd = 0.f;
#pragma unroll
    for (int c = 0; c < C; c += 4) {
        float4 v = ld4(&row[c]);
        float4 as = *reinterpret_cast<const float4*>(&a_src[hd * C + c]);
        float4 ad = *reinterpret_cast<const float4*>(&a_dst[hd * C + c]);
        ss += v.x * as.x + v.y * as.y + v.z * as.z + v.w * as.w;
        sd += v.x * ad.x + v.y * ad.y + v.z * ad.z + v.w * ad.w;
    }
    al_s[idx] = ss;
    al_d[idx] = sd;
}

// ---------------- per-edge softmax weights ----------------
__global__ void ew_kernel(const float* __restrict__ als, const float* __restrict__ ald,
                          const int* __restrict__ rowptr, const int* __restrict__ csr,
                          float* __restrict__ wgt, int N) {
    int wave = (blockIdx.x * blockDim.x + threadIdx.x) >> 6;
    int lane = threadIdx.x & 63;
    if (wave >= N) return;
    int h = lane & 3, eo = lane >> 2;
    float aldv = ald[wave * 4 + h];
    int beg = rowptr[wave], end = rowptr[wave + 1];
    for (int k = beg + eo; k < end; k += 16) {
        int j = csr[k];
        float e = als[j * 4 + h] + aldv;
        e = fmaxf(e, 0.2f * e);
        wgt[(size_t)k * 4 + h] = __expf(e);
    }
}

// ---------------- pre-aggregation (wave per node), precomputed weights ----------------
template <int K, typename TIN, typename TOUT>
__global__ void preagg_kernel(const TIN* __restrict__ x, const float* __restrict__ wgt,
                              const int* __restrict__ rowptr, const int* __restrict__ csr,
                              TOUT* __restrict__ agg, int N) {
    constexpr int V = K / 64;
    int wave = (blockIdx.x * blockDim.x + threadIdx.x) >> 6;
    int lane = threadIdx.x & 63;
    if (wave >= N) return;
    float s0 = 0.f, s1 = 0.f, s2 = 0.f, s3 = 0.f;
    float acc[4][V] = {};
    int beg = rowptr[wave], end = rowptr[wave + 1];
    int k = beg;
    for (; k + 2 <= end; k += 2) {
        int j0 = csr[k], j1 = csr[k + 1];
        float4 w0 = *reinterpret_cast<const float4*>(&wgt[(size_t)k * 4]);
        float4 w1 = *reinterpret_cast<const float4*>(&wgt[(size_t)(k + 1) * 4]);
        s0 += w0.x + w1.x; s1 += w0.y + w1.y; s2 += w0.z + w1.z; s3 += w0.w + w1.w;
        if (V == 1) {
            float v0 = ld1(&x[(size_t)j0 * K + lane]);
            float v1 = ld1(&x[(size_t)j1 * K + lane]);
            acc[0][0] += w0.x * v0 + w1.x * v1;
            acc[1][0] += w0.y * v0 + w1.y * v1;
            acc[2][0] += w0.z * v0 + w1.z * v1;
            acc[3][0] += w0.w * v0 + w1.w * v1;
        } else {
            float2 v0 = ld2(&x[(size_t)j0 * K + lane * 2]);
            float2 v1 = ld2(&x[(size_t)j1 * K + lane * 2]);
            acc[0][0] += w0.x * v0.x + w1.x * v1.x; acc[0][1] += w0.x * v0.y + w1.x * v1.y;
            acc[1][0] += w0.y * v0.x + w1.y * v1.x; acc[1][1] += w0.y * v0.y + w1.y * v1.y;
            acc[2][0] += w0.z * v0.x + w1.z * v1.x; acc[2][1] += w0.z * v0.y + w1.z * v1.y;
            acc[3][0] += w0.w * v0.x + w1.w * v1.x; acc[3][1] += w0.w * v0.y + w1.w * v1.y;
        }
    }
    if (k < end) {
        int j0 = csr[k];
        float4 w0 = *reinterpret_cast<const float4*>(&wgt[(size_t)k * 4]);
        s0 += w0.x; s1 += w0.y; s2 += w0.z; s3 += w0.w;
        if (V == 1) {
            float v0 = ld1(&x[(size_t)j0 * K + lane]);
            acc[0][0] += w0.x * v0; acc[1][0] += w0.y * v0;
            acc[2][0] += w0.z * v0; acc[3][0] += w0.w * v0;
        } else {
            float2 v0 = ld2(&x[(size_t)j0 * K + lane * 2]);
            acc[0][0] += w0.x * v0.x; acc[0][1] += w0.x * v0.y;
            acc[1][0] += w0.y * v0.x; acc[1][1] += w0.y * v0.y;
            acc[2][0] += w0.z * v0.x; acc[2][1] += w0.z * v0.y;
            acc[3][0] += w0.w * v0.x; acc[3][1] += w0.w * v0.y;
        }
    }
    float inv[4] = {1.f / (s0 + 1e-16f), 1.f / (s1 + 1e-16f),
                    1.f / (s2 + 1e-16f), 1.f / (s3 + 1e-16f)};
    size_t o = (size_t)wave * 4 * K;
#pragma unroll
    for (int h = 0; h < 4; ++h) {
        if (V == 1) {
            st1(&agg[o + h * K + lane], acc[h][0] * inv[h]);
        } else {
            st2(&agg[o + h * K + lane * 2], acc[h][0] * inv[h], acc[h][1] * inv[h]);
        }
    }
}

// ---------------- post-GEMM aggregation, interleaved heads, precomputed weights ----------------
template <int C, typename TIN, typename TOUT>
__global__ void aggregate_kernel(const TIN* __restrict__ h, const float* __restrict__ wgt,
                                 const int* __restrict__ rowptr, const int* __restrict__ csr,
                                 const float* __restrict__ bias, TOUT* __restrict__ outp, int N) {
    constexpr int VPT = 4 * C / 64;
    int wave = (blockIdx.x * blockDim.x + threadIdx.x) >> 6;
    int lane = threadIdx.x & 63;
    if (wave >= N) return;
    int head = lane >> 4;
    int c0 = (lane & 15) * VPT;
    const TIN* hb = h + head * C + c0;

    float s = 0.f;
    float acc[VPT] = {};
    int beg = rowptr[wave], end = rowptr[wave + 1];
    int k = beg;
    for (; k + 2 <= end; k += 2) {
        int j0 = csr[k], j1 = csr[k + 1];
        float w0 = wgt[(size_t)k * 4 + head];
        float w1 = wgt[(size_t)(k + 1) * 4 + head];
        s += w0 + w1;
        if (VPT == 4) {
            float4 v0 = ld4(hb + (size_t)j0 * (4 * C));
            float4 v1 = ld4(hb + (size_t)j1 * (4 * C));
            acc[0] += w0 * v0.x + w1 * v1.x; acc[1] += w0 * v0.y + w1 * v1.y;
            acc[2] += w0 * v0.z + w1 * v1.z; acc[3] += w0 * v0.w + w1 * v1.w;
        } else {
            float2 v0 = ld2(hb + (size_t)j0 * (4 * C));
            float2 v1 = ld2(hb + (size_t)j1 * (4 * C));
            acc[0] += w0 * v0.x + w1 * v1.x; acc[1] += w0 * v0.y + w1 * v1.y;
        }
    }
    if (k < end) {
        int j0 = csr[k];
        float w0 = wgt[(size_t)k * 4 + head];
        s += w0;
        if (VPT == 4) {
            float4 v0 = ld4(hb + (size_t)j0 * (4 * C));
            acc[0] += w0 * v0.x; acc[1] += w0 * v0.y; acc[2] += w0 * v0.z; acc[3] += w0 * v0.w;
        } else {
            float2 v0 = ld2(hb + (size_t)j0 * (4 * C));
            acc[0] += w0 * v0.x; acc[1] += w0 * v0.y;
        }
    }
    float inv = 1.f / (s + 1e-16f);
    size_t o = (size_t)wave * (4 * C) + head * C + c0;
    if (VPT == 2) {
        st2(&outp[o], acc[0] * inv + bias[head * C + c0],
                      acc[1] * inv + bias[head * C + c0 + 1]);
    } else {
#pragma unroll
        for (int j = 0; j < VPT; ++j)
            st1(&outp[o + j], acc[j] * inv + bias[head * C + c0 + j]);
    }
}

// ---------------- fallback f32 aggregation ----------------
template <int C, bool MEAN>
__global__ void aggregate_f32_kernel(const float* __restrict__ h,
                                     const float* __restrict__ al_s, const float* __restrict__ al_d,
                                     const int* __restrict__ rowptr, const int* __restrict__ csr_src,
                                     const float* __restrict__ bias,
                                     float* __restrict__ outf, int N) {
    constexpr int VPT = 4 * C / 64;
    int wave = (blockIdx.x * blockDim.x + threadIdx.x) >> 6;
    int lane = threadIdx.x & 63;
    if (wave >= N) return;
    int head = lane >> 4;
    int c0 = (lane & 15) * VPT;
    const float* hb = h + head * C + c0;
    float ald = al_d[wave * HEADS + head];
    float s = 0.f;
    float acc[VPT] = {};
    int beg = rowptr[wave], end = rowptr[wave + 1];
    for (int k = beg; k < end; ++k) {
        int s0 = csr_src[k];
        float e0 = al_s[s0 * HEADS + head] + ald;
        e0 = fmaxf(e0, 0.2f * e0);
        float w0 = __expf(e0);
        s += w0;
        const float* p0 = hb + (size_t)s0 * (HEADS * C);
#pragma unroll
        for (int j = 0; j < VPT; ++j) acc[j] += w0 * p0[j];
    }
    float inv = 1.f / (s + 1e-16f);
    if (!MEAN) {
        size_t o = (size_t)wave * (HEADS * C) + head * C + c0;
#pragma unroll
        for (int j = 0; j < VPT; ++j)
            outf[o + j] = acc[j] * inv + bias[head * C + c0 + j];
    } else {
        float v[VPT];
#pragma unroll
        for (int j = 0; j < VPT; ++j) {
            float t = acc[j] * inv;
            t += __shfl_xor(t, 16);
            t += __shfl_xor(t, 32);
            v[j] = t * 0.25f + bias[c0 + j];
        }
        if (lane < 16) {
#pragma unroll
            for (int j = 0; j < VPT; ++j)
                outf[(size_t)wave * C + c0 + j] = v[j];
        }
    }
}

// ---------------- W3 restack with head-mean folded ----------------
__global__ void wstk_kernel(const float* __restrict__ W3, float* __restrict__ Wstk) {
    int idx = blockIdx.x * blockDim.x + threadIdx.x;
    if (idx >= 512 * 64) return;
    int c = idx & 63;
    int hk = idx >> 6;
    int h = hk >> 7, k = hk & 127;
    Wstk[idx] = W3[(size_t)k * 256 + h * 64 + c] * 0.25f;
}

// ---------------- MFMA GEMM: O[N, col0..+63] = A[N, aOff..+K) @ Bt^T, BM=128 BN=64 BK=32 ----------------
// A bf16 [N][lda], Bt bf16 [M][K] (pre-transposed weight). 4 waves; wave owns 32 rows.
template <typename TOUT>
__global__ __launch_bounds__(256) void mfma_gemm_kernel(
    const __hip_bfloat16* __restrict__ A, int lda, int aSel,
    const __hip_bfloat16* __restrict__ Bt,
    TOUT* __restrict__ O, int ldo,
    const float* __restrict__ bias, int N, int K) {
    __shared__ __hip_bfloat16 As[128][40];  // row stride 80B = 20 banks -> 2-way max
    __shared__ __hip_bfloat16 Bs[64][40];
    int col0 = blockIdx.x * 64;
    int row0 = blockIdx.y * 128;
    int aOff = aSel ? col0 : 0;
    int tid = threadIdx.x;
    int wv = tid >> 6, lane = tid & 63;
    int g = lane >> 4, l16 = lane & 15;
    f32x4 acc[2][4] = {};

    for (int k0 = 0; k0 < K; k0 += 32) {
        // stage A: 128 rows x 32 bf16 (2 x uint4 per row), 512 vec-loads over 256 threads
#pragma unroll
        for (int i = 0; i < 2; ++i) {
            int idx = tid + i * 256;
            int r = idx >> 2, h4 = idx & 3;
            int gr = row0 + r;
            uint4 v = make_uint4(0, 0, 0, 0);
            if (gr < N) v = *reinterpret_cast<const uint4*>(&A[(size_t)gr * lda + aOff + k0 + h4 * 8]);
            *reinterpret_cast<uint4*>(&As[r][h4 * 8]) = v;
        }
        // stage B: 64 rows x 32 bf16, 256 vec-loads
        {
            int r = tid >> 2, h4 = tid & 3;
            uint4 v = *reinterpret_cast<const uint4*>(&Bt[(size_t)(col0 + r) * K + k0 + h4 * 8]);
            *reinterpret_cast<uint4*>(&Bs[r][h4 * 8]) = v;
        }
        __syncthreads();
        s16x8 af[2], bf[4];
#pragma unroll
        for (int m = 0; m < 2; ++m)
            af[m] = *reinterpret_cast<const s16x8*>(&As[wv * 32 + m * 16 + l16][g * 8]);
#pragma unroll
        for (int n = 0; n < 4; ++n)
            bf[n] = *reinterpret_cast<const s16x8*>(&Bs[n * 16 + l16][g * 8]);
#pragma unroll
        for (int m = 0; m < 2; ++m)
#pragma unroll
            for (int n = 0; n < 4; ++n)
                acc[m][n] = __builtin_amdgcn_mfma_f32_16x16x32_bf16(af[m], bf[n], acc[m][n], 0, 0, 0);
        __syncthreads();
    }
    // epilogue: C/D layout col=lane&15, row=g*4+reg (m89-verified)
#pragma unroll
    for (int m = 0; m < 2; ++m) {
#pragma unroll
        for (int rr = 0; rr < 4; ++rr) {
            int row = row0 + wv * 32 + m * 16 + g * 4 + rr;
            if (row < N) {
#pragma unroll
                for (int n = 0; n < 4; ++n) {
                    int col = col0 + n * 16 + l16;
                    float v = acc[m][n][rr];
                    if (bias) v += bias[col];
                    st1(&O[(size_t)row * ldo + col], v);
                }
            }
        }
    }
}

// ---------------- fallback f32 GEMM (BM=128 BN=64) ----------------
__global__ __launch_bounds__(256) void gemm64_kernel(const float* __restrict__ A, int lda, int aSel,
                                                     const float* __restrict__ B, int ldb,
                                                     float* __restrict__ O, int ldo,
                                                     const float* __restrict__ bias,
                                                     int N, int K) {
    __shared__ float As[16][132];
    __shared__ float Bs[16][68];
    int col0 = blockIdx.x * 64;
    int row0 = blockIdx.y * 128;
    int aOff = aSel ? col0 : 0;
    int tid = threadIdx.x;
    int tx = tid & 15, ty = tid >> 4;
    float acc[8][4] = {};
    for (int k0 = 0; k0 < K; k0 += 16) {
        for (int i = tid; i < 512; i += 256) {
            int r = i >> 2, kc = (i & 3) * 4;
            int gr = row0 + r;
            float4 v = make_float4(0.f, 0.f, 0.f, 0.f);
            if (gr < N) v = *reinterpret_cast<const float4*>(&A[(size_t)gr * lda + aOff + k0 + kc]);
            As[kc + 0][r] = v.x; As[kc + 1][r] = v.y;
            As[kc + 2][r] = v.z; As[kc + 3][r] = v.w;
        }
        {
            int k = tid >> 4, c4 = (tid & 15) * 4;
            float4 v = *reinterpret_cast<const float4*>(&B[(size_t)(k0 + k) * ldb + col0 + c4]);
            *reinterpret_cast<float4*>(&Bs[k][c4]) = v;
        }
        __syncthreads();
#pragma unroll
        for (int k = 0; k < 16; ++k) {
            float4 a0 = *reinterpret_cast<const float4*>(&As[k][ty * 8]);
            float4 a1 = *reinterpret_cast<const float4*>(&As[k][ty * 8 + 4]);
            float4 b0 = *reinterpret_cast<const float4*>(&Bs[k][tx * 4]);
            float ar[8] = {a0.x, a0.y, a0.z, a0.w, a1.x, a1.y, a1.z, a1.w};
            float br[4] = {b0.x, b0.y, b0.z, b0.w};
#pragma unroll
            for (int i = 0; i < 8; ++i)
#pragma unroll
                for (int j = 0; j < 4; ++j) acc[i][j] += ar[i] * br[j];
        }
        __syncthreads();
    }
    float4 bv = make_float4(0.f, 0.f, 0.f, 0.f);
    if (bias) bv = *reinterpret_cast<const float4*>(&bias[col0 + tx * 4]);
#pragma unroll
    for (int i = 0; i < 8; ++i) {
        int r = row0 + ty * 8 + i;
        if (r < N) {
            float4 v = make_float4(acc[i][0] + bv.x, acc[i][1] + bv.y,
                                   acc[i][2] + bv.z, acc[i][3] + bv.w);
            *reinterpret_cast<float4*>(&O[(size_t)r * ldo + col0 + tx * 4]) = v;
        }
    }
}

// ---------------- launch ----------------
extern "C" void kernel_launch(void* const* d_in, const int* in_sizes, int n_in,
                              void* d_out, int out_size, void* d_ws, size_t ws_size,
                              hipStream_t stream) {
    const float* x      = (const float*)d_in[0];
    const int*   eidx   = (const int*)d_in[1];
    const float* W1     = (const float*)d_in[2];
    const float* a1_src = (const float*)d_in[3];
    const float* a1_dst = (const float*)d_in[4];
    const float* b1     = (const float*)d_in[5];
    const float* W2     = (const float*)d_in[6];
    const float* a2_src = (const float*)d_in[7];
    const float* a2_dst = (const float*)d_in[8];
    const float* b2     = (const float*)d_in[9];
    const float* W3     = (const float*)d_in[10];
    const float* a3_src = (const float*)d_in[11];
    const float* a3_dst = (const float*)d_in[12];
    const float* b3     = (const float*)d_in[13];
    float* out = (float*)d_out;

    const int N = in_sizes[0] / 64;      // 50000
    const int E = in_sizes[1] / 2;       // 800000
    const int NB = (N + 1023) / 1024;

    // ---- workspace: ints, small floats (incl. Bt weights), then arena F ----
    int* rowptr = (int*)d_ws;
    int* deg    = rowptr + (N + 1);
    int* cursor = deg + N;
    int* csr    = cursor + N;
    int* flag   = csr + E;
    int* bsum   = flag + 1;
    int* boff   = bsum + NB;
    uintptr_t pa = (uintptr_t)(boff + NB);
    pa = (pa + 255) & ~(uintptr_t)255;
    float* als  = (float*)pa;                       // N*4
    float* ald  = als + (size_t)N * 4;              // N*4
    float* ps   = ald + (size_t)N * 4;              // 512
    float* pd   = ps + 512;                         // 512
    float* Wstk = pd + 512;                         // 512*64
    __hip_bfloat16* Bt1 = (__hip_bfloat16*)(Wstk + 512 * 64);  // 256*64
    __hip_bfloat16* Bt2 = Bt1 + 256 * 64;                      // 128*256
    __hip_bfloat16* Bt3 = Bt2 + 128 * 256;                     // 64*512
    uintptr_t pf = (uintptr_t)(Bt3 + 64 * 512);
    pf = (pf + 255) & ~(uintptr_t)255;
    float* F    = (float*)pf;

    size_t base_bytes = (pf - (uintptr_t)d_ws);
    size_t need = ((size_t)N * 576 + (size_t)E * 4) * sizeof(float);
    bool full = ws_size >= base_bytes + need;

    // ---- CSR build ----
    detect_kernel<<<1, 64, 0, stream>>>(eidx, flag);
    hipMemsetAsync(deg, 0, (size_t)N * sizeof(int), stream);
    deg_kernel<<<(E + 255) / 256, 256, 0, stream>>>(eidx, flag, deg, E, N);
    reduce_kernel<<<NB, 256, 0, stream>>>(deg, bsum, N);
    scan_bsum_kernel<<<1, 64, 0, stream>>>(bsum, boff, NB, rowptr + N);
    block_scan_kernel<<<NB, 256, 0, stream>>>(deg, boff, rowptr, cursor, N);
    scatter_kernel<<<(E + 255) / 256, 256, 0, stream>>>(eidx, flag, cursor, csr, E, N);

    const int alBlocks  = (N * HEADS + 255) / 256;
    const int aggBlocks = (N + 3) / 4;
    const int rowB128   = (N + 127) / 128;

    if (full) {
        // arena (float units), all regions disjoint:
        float* base = F;
        __hip_bfloat16* xb    = (__hip_bfloat16*)(base);                  // N*64 bf16 = 32N f
        float*          wgt   = base + (size_t)N * 32;                    // E*4 f = 64N f
        __hip_bfloat16* agg1b = (__hip_bfloat16*)(base + (size_t)N * 96); // N*256 bf16 = 128N f... (32N used)
        // careful sizes: agg1b N*256 bf16 = 128N f
        __hip_bfloat16* out1b = (__hip_bfloat16*)(base + (size_t)N * 224); // N*256 bf16 = 128N f
        __hip_bfloat16* h2b   = (__hip_bfloat16*)(base + (size_t)N * 352); // N*128 bf16 = 64N f
        __hip_bfloat16* out2b = (__hip_bfloat16*)(base + (size_t)N * 416); // N*128 bf16 = 64N f
        __hip_bfloat16* agg3  = (__hip_bfloat16*)(base + (size_t)N * 480); // N*512 bf16 = 256N f  (total 736N? no)
        // NOTE: total = 32+64+128+128+64+64+256 = 736N > 640N budget? Recompute `need` accordingly.
        // (need was set to 576N+4E = 640N; adjust: we keep the larger layout only if it fits)
        // Fallback to overlap-free smaller plan if not.

        // weights prep
        wtb_kernel<<<(64 * 256 + 255) / 256, 256, 0, stream>>>(W1, Bt1, 64, 256);
        wtb_kernel<<<(256 * 128 + 255) / 256, 256, 0, stream>>>(W2, Bt2, 256, 128);
        wstk_kernel<<<128, 256, 0, stream>>>(W3, Wstk);
        wtb_kernel<<<(512 * 64 + 255) / 256, 256, 0, stream>>>(Wstk, Bt3, 512, 64);

        // layer 1
        f2b_kernel<<<(N * 64 / 8 + 255) / 256, 256, 0, stream>>>(x, xb, N * 64 / 8);
        proj_kernel<<<1, 256, 0, stream>>>(W1, a1_src, a1_dst, ps, pd, 64, 256, 64);
        alx_kernel<64, float><<<alBlocks, 256, 0, stream>>>(x, ps, pd, als, ald, N);
        ew_kernel<<<aggBlocks, 256, 0, stream>>>(als, ald, rowptr, csr, wgt, N);
        preagg_kernel<64, __hip_bfloat16, __hip_bfloat16><<<aggBlocks, 256, 0, stream>>>(xb, wgt, rowptr, csr, agg1b, N);
        mfma_gemm_kernel<__hip_bfloat16><<<dim3(4, rowB128), 256, 0, stream>>>(agg1b, 256, 1, Bt1, out1b, 256, b1, N, 64);

        // layer 2
        mfma_gemm_kernel<__hip_bfloat16><<<dim3(2, rowB128), 256, 0, stream>>>(out1b, 256, 0, Bt2, h2b, 128, nullptr, N, 256);
        al_kernel<32, __hip_bfloat16><<<alBlocks, 256, 0, stream>>>(h2b, a2_src, a2_dst, als, ald, N);
        ew_kernel<<<aggBlocks, 256, 0, stream>>>(als, ald, rowptr, csr, wgt, N);
        aggregate_kernel<32, __hip_bfloat16, __hip_bfloat16><<<aggBlocks, 256, 0, stream>>>(h2b, wgt, rowptr, csr, b2, out2b, N);

        // layer 3
        proj_kernel<<<2, 256, 0, stream>>>(W3, a3_src, a3_dst, ps, pd, 128, 256, 64);
        alx_kernel<128, __hip_bfloat16><<<alBlocks, 256, 0, stream>>>(out2b, ps, pd, als, ald, N);
        ew_kernel<<<aggBlocks, 256, 0, stream>>>(als, ald, rowptr, csr, wgt, N);
        preagg_kernel<128, __hip_bfloat16, __hip_bfloat16><<<aggBlocks, 256, 0, stream>>>(out2b, wgt, rowptr, csr, agg3, N);
        mfma_gemm_kernel<float><<<dim3(1, rowB128), 256, 0, stream>>>(agg3, 512, 0, Bt3, out, 64, b3, N, 512);
    } else {
        // fallback: all-f32, overlap-free within 640N floats
        float* tmp1 = F;                        // [N,256] x@W1
        float* h1   = F + (size_t)N * 256;      // [N,256] aggregated L1 out
        float* h2   = F + (size_t)N * 512;      // [N,128]
        float* out2 = F + (size_t)N * 576;      // [N,128] -> 640N total
        gemm64_kernel<<<dim3(4, rowB128), 256, 0, stream>>>(x, 64, 0, W1, 256, tmp1, 256, nullptr, N, 64);
        al_kernel<64, float><<<alBlocks, 256, 0, stream>>>(tmp1, a1_src, a1_dst, als, ald, N);
        aggregate_f32_kernel<64, false><<<aggBlocks, 256, 0, stream>>>(tmp1, als, ald, rowptr, csr, b1, h1, N);
        gemm64_kernel<<<dim3(2, rowB128), 256, 0, stream>>>(h1, 256, 0, W2, 128, h2, 128, nullptr, N, 256);
        al_kernel<32, float><<<alBlocks, 256, 0, stream>>>(h2, a2_src, a2_dst, als, ald, N);
        aggregate_f32_kernel<32, false><<<aggBlocks, 256, 0, stream>>>(h2, als, ald, rowptr, csr, b2, out2, N);
        gemm64_kernel<<<dim3(4, rowB128), 256, 0, stream>>>(out2, 128, 0, W3, 256, tmp1, 256, nullptr, N, 128);
        al_kernel<64, float><<<alBlocks, 256, 0, stream>>>(tmp1, a3_src, a3_dst, als, ald, N);
        aggregate_f32_kernel<64, true><<<aggBlocks, 256, 0, stream>>>(tmp1, als, ald, rowptr, csr, b3, out, N);
    }
}

// Round 10
// 394.861 us; speedup vs baseline: 2.1188x; 1.1862x over previous
//
#include <hip/hip_runtime.h>
#include <hip/hip_bf16.h>

#define HEADS 4

typedef __attribute__((ext_vector_type(4))) float f32x4;
typedef __attribute__((ext_vector_type(8))) short s16x8;

// ---------------- bf16 helpers ----------------
__device__ __forceinline__ float u2f(unsigned short u) {
    return __uint_as_float(((unsigned)u) << 16);
}
__device__ __forceinline__ unsigned short rne(float v) {
    unsigned b = __float_as_uint(v);
    return (unsigned short)((b + 0x7FFF + ((b >> 16) & 1)) >> 16);
}
__device__ __forceinline__ float ld1(const float* p) { return *p; }
__device__ __forceinline__ float ld1(const __hip_bfloat16* p) {
    return u2f(*reinterpret_cast<const unsigned short*>(p));
}
__device__ __forceinline__ float2 ld2(const float* p) { return *reinterpret_cast<const float2*>(p); }
__device__ __forceinline__ float2 ld2(const __hip_bfloat16* p) {
    ushort2 u = *reinterpret_cast<const ushort2*>(p);
    return make_float2(u2f(u.x), u2f(u.y));
}
__device__ __forceinline__ float4 ld4(const float* p) { return *reinterpret_cast<const float4*>(p); }
__device__ __forceinline__ float4 ld4(const __hip_bfloat16* p) {
    ushort4 u = *reinterpret_cast<const ushort4*>(p);
    return make_float4(u2f(u.x), u2f(u.y), u2f(u.z), u2f(u.w));
}
__device__ __forceinline__ void st1(float* p, float v) { *p = v; }
__device__ __forceinline__ void st1(__hip_bfloat16* p, float v) {
    *reinterpret_cast<unsigned short*>(p) = rne(v);
}
__device__ __forceinline__ void st2(float* p, float a, float b) {
    *reinterpret_cast<float2*>(p) = make_float2(a, b);
}
__device__ __forceinline__ void st2(__hip_bfloat16* p, float a, float b) {
    *reinterpret_cast<ushort2*>(p) = make_ushort2(rne(a), rne(b));
}
__device__ __forceinline__ void st4(float* p, float4 v) { *reinterpret_cast<float4*>(p) = v; }
__device__ __forceinline__ void st4(__hip_bfloat16* p, float4 v) {
    *reinterpret_cast<ushort4*>(p) = make_ushort4(rne(v.x), rne(v.y), rne(v.z), rne(v.w));
}

// ---------------- edge dtype detection ----------------
__global__ void detect_kernel(const int* __restrict__ eidx, int* __restrict__ flag) {
    if (blockIdx.x == 0 && threadIdx.x == 0) {
        int orv = 0;
        for (int i = 0; i < 256; ++i) orv |= eidx[2 * i + 1];
        *flag = (orv == 0) ? 1 : 0;
    }
}
__device__ __forceinline__ int edge_elem(const int* e, size_t idx, int is64) {
    return is64 ? e[2 * idx] : e[idx];
}

// ---------------- CSR build ----------------
__global__ void deg_kernel(const int* __restrict__ eidx, const int* __restrict__ flag,
                           int* __restrict__ deg, int E, int N) {
    int e = blockIdx.x * blockDim.x + threadIdx.x;
    if (e < E) {
        int is64 = *flag;
        int d = edge_elem(eidx, (size_t)E + e, is64);
        if ((unsigned)d < (unsigned)N) atomicAdd(&deg[d], 1);
    }
}

__global__ void reduce_kernel(const int* __restrict__ deg, int* __restrict__ bsum, int n) {
    __shared__ int sdata[256];
    int base = blockIdx.x * 1024;
    int t = threadIdx.x;
    int v = 0;
#pragma unroll
    for (int j = 0; j < 4; ++j) {
        int i = base + t + j * 256;
        if (i < n) v += deg[i];
    }
    sdata[t] = v;
    __syncthreads();
    for (int off = 128; off > 0; off >>= 1) {
        if (t < off) sdata[t] += sdata[t + off];
        __syncthreads();
    }
    if (t == 0) bsum[blockIdx.x] = sdata[0];
}

__global__ void scan_bsum_kernel(const int* __restrict__ bsum, int* __restrict__ boff,
                                 int nb, int* __restrict__ totalp) {
    int lane = threadIdx.x;
    int carry = 0;
    for (int base = 0; base < nb; base += 64) {
        int i = base + lane;
        int v = (i < nb) ? bsum[i] : 0;
        int inc = v;
        for (int off = 1; off < 64; off <<= 1) {
            int tt = __shfl_up(inc, off);
            if (lane >= off) inc += tt;
        }
        if (i < nb) boff[i] = carry + inc - v;
        carry += __shfl(inc, 63);
    }
    if (lane == 0) *totalp = carry;
}

__global__ void block_scan_kernel(const int* __restrict__ deg, const int* __restrict__ boff,
                                  int* __restrict__ rowptr, int* __restrict__ cursor, int n) {
    __shared__ int wsum[4];
    int base = blockIdx.x * 1024;
    int t = threadIdx.x;
    int lane = t & 63, w = t >> 6;
    int v[4];
    int lsum = 0;
#pragma unroll
    for (int j = 0; j < 4; ++j) {
        int i = base + t * 4 + j;
        v[j] = (i < n) ? deg[i] : 0;
        lsum += v[j];
    }
    int inc = lsum;
    for (int off = 1; off < 64; off <<= 1) {
        int tt = __shfl_up(inc, off);
        if (lane >= off) inc += tt;
    }
    if (lane == 63) wsum[w] = inc;
    __syncthreads();
    int woff = 0;
    for (int i = 0; i < w; ++i) woff += wsum[i];
    int ex = boff[blockIdx.x] + woff + inc - lsum;
#pragma unroll
    for (int j = 0; j < 4; ++j) {
        int i = base + t * 4 + j;
        if (i < n) { rowptr[i] = ex; cursor[i] = ex; }
        ex += v[j];
    }
}

__global__ void scatter_kernel(const int* __restrict__ eidx, const int* __restrict__ flag,
                               int* __restrict__ cursor, int* __restrict__ csr_src, int E, int N) {
    int e = blockIdx.x * blockDim.x + threadIdx.x;
    if (e < E) {
        int is64 = *flag;
        int s = edge_elem(eidx, (size_t)e, is64);
        int d = edge_elem(eidx, (size_t)E + e, is64);
        if ((unsigned)d < (unsigned)N && (unsigned)s < (unsigned)N) {
            int pos = atomicAdd(&cursor[d], 1);
            csr_src[pos] = s;
        }
    }
}

// ---------------- fused prep: xb, Bt1, Bt2, Bt3 (with 0.25 mean fold), proj1, proj3 ----------------
__global__ void prep_kernel(const float* __restrict__ x,
                            const float* __restrict__ W1, const float* __restrict__ W2,
                            const float* __restrict__ W3,
                            const float* __restrict__ a1s, const float* __restrict__ a1d,
                            const float* __restrict__ a3s, const float* __restrict__ a3d,
                            __hip_bfloat16* __restrict__ xb,
                            __hip_bfloat16* __restrict__ Bt1, __hip_bfloat16* __restrict__ Bt2,
                            __hip_bfloat16* __restrict__ Bt3,
                            float* __restrict__ ps1, float* __restrict__ pd1,
                            float* __restrict__ ps3, float* __restrict__ pd3, int n8) {
    int b = blockIdx.x, t = threadIdx.x;
    int nXB = (n8 + 255) / 256;
    if (b < nXB) {
        int i = b * 256 + t;
        if (i < n8) {
            float4 a = *reinterpret_cast<const float4*>(&x[(size_t)i * 8]);
            float4 c = *reinterpret_cast<const float4*>(&x[(size_t)i * 8 + 4]);
            st4(&xb[(size_t)i * 8], a);
            st4(&xb[(size_t)i * 8 + 4], c);
        }
        return;
    }
    b -= nXB;
    if (b < 64) {  // Bt1 [256][64]: Bt1[m*64+k] = W1[k*256+m]
        int idx = b * 256 + t;
        int m = idx >> 6, k = idx & 63;
        st1(&Bt1[idx], W1[(size_t)k * 256 + m]);
        return;
    }
    b -= 64;
    if (b < 128) {  // Bt2 [128][256]: Bt2[m*256+k] = W2[k*128+m]
        int idx = b * 256 + t;
        int m = idx >> 8, k = idx & 255;
        st1(&Bt2[idx], W2[(size_t)k * 128 + m]);
        return;
    }
    b -= 128;
    if (b < 128) {  // Bt3 [64][512]: Bt3[c*512 + h*128+kk] = W3[kk*256 + h*64 + c] * 0.25
        int idx = b * 256 + t;
        int c = idx >> 9, r = idx & 511;
        int h = r >> 7, kk = r & 127;
        st1(&Bt3[idx], W3[(size_t)kk * 256 + h * 64 + c] * 0.25f);
        return;
    }
    b -= 128;
    if (b < 1) {  // proj1: ps1[h*64+k] = sum_c W1[k*256 + h*64+c]*a1s[h*64+c]
        int h = t >> 6, k = t & 63;
        float ss = 0.f, sd = 0.f;
        for (int c = 0; c < 64; ++c) {
            float w = W1[(size_t)k * 256 + h * 64 + c];
            ss += w * a1s[h * 64 + c];
            sd += w * a1d[h * 64 + c];
        }
        ps1[t] = ss;
        pd1[t] = sd;
        return;
    }
    b -= 1;
    if (b < 2) {  // proj3: ps3[h*128+k] = sum_c W3[k*256 + h*64+c]*a3s[h*64+c]
        int idx = b * 256 + t;  // < 512
        int h = idx >> 7, k = idx & 127;
        float ss = 0.f, sd = 0.f;
        for (int c = 0; c < 64; ++c) {
            float w = W3[(size_t)k * 256 + h * 64 + c];
            ss += w * a3s[h * 64 + c];
            sd += w * a3d[h * 64 + c];
        }
        ps3[idx] = ss;
        pd3[idx] = sd;
        return;
    }
}

// ---------------- logits from raw features ----------------
template <int K, typename T>
__global__ void alx_kernel(const T* __restrict__ x, const float* __restrict__ ps,
                           const float* __restrict__ pd, float* __restrict__ als,
                           float* __restrict__ ald, int N) {
    int idx = blockIdx.x * blockDim.x + threadIdx.x;
    if (idx >= N * 4) return;
    int n = idx >> 2, h = idx & 3;
    const T* row = x + (size_t)n * K;
    const float* vs = ps + h * K;
    const float* vd = pd + h * K;
    float ss = 0.f, sd = 0.f;
#pragma unroll
    for (int c = 0; c < K; c += 4) {
        float4 v = ld4(&row[c]);
        float4 a = *reinterpret_cast<const float4*>(&vs[c]);
        float4 b = *reinterpret_cast<const float4*>(&vd[c]);
        ss += v.x * a.x + v.y * a.y + v.z * a.z + v.w * a.w;
        sd += v.x * b.x + v.y * b.y + v.z * b.z + v.w * b.w;
    }
    als[idx] = ss;
    ald[idx] = sd;
}

// ---------------- logits from interleaved head features (L2) ----------------
template <int C, typename T>
__global__ void al_kernel(const T* __restrict__ h,
                          const float* __restrict__ a_src, const float* __restrict__ a_dst,
                          float* __restrict__ al_s, float* __restrict__ al_d, int N) {
    int idx = blockIdx.x * blockDim.x + threadIdx.x;
    if (idx >= N * HEADS) return;
    int n = idx >> 2, hd = idx & 3;
    const T* row = h + (size_t)n * HEADS * C + hd * C;
    float ss = 0.f, sd = 0.f;
#pragma unroll
    for (int c = 0; c < C; c += 4) {
        float4 v = ld4(&row[c]);
        float4 as = *reinterpret_cast<const float4*>(&a_src[hd * C + c]);
        float4 ad = *reinterpret_cast<const float4*>(&a_dst[hd * C + c]);
        ss += v.x * as.x + v.y * as.y + v.z * as.z + v.w * as.w;
        sd += v.x * ad.x + v.y * ad.y + v.z * ad.z + v.w * ad.w;
    }
    al_s[idx] = ss;
    al_d[idx] = sd;
}

// ---------------- fused gather (pre-agg): weights computed in-wave via shuffles ----------------
// x[N][K] shared across heads; out agg[N][4*K] (h-major). One wave per node.
// Producer: lane l computes w for edge (l>>2), head (l&3) of the current 16-edge chunk.
template <int K, typename TIN, typename TOUT>
__global__ void gather_pre_kernel(const TIN* __restrict__ x, const float* __restrict__ als,
                                  const float* __restrict__ ald, const int* __restrict__ rowptr,
                                  const int* __restrict__ csr, TOUT* __restrict__ agg, int N) {
    constexpr int V = K / 64;  // 1 (K=64) or 2 (K=128)
    int wave = (blockIdx.x * blockDim.x + threadIdx.x) >> 6;
    int lane = threadIdx.x & 63;
    if (wave >= N) return;
    int h4 = lane & 3, e4 = lane >> 2;
    float aldv = ald[wave * 4 + h4];
    float s0 = 0.f, s1 = 0.f, s2 = 0.f, s3 = 0.f;
    float acc[4][V] = {};
    int beg = rowptr[wave], end = rowptr[wave + 1];
    for (int kc = beg; kc < end; kc += 16) {
        int cnt = end - kc;
        if (cnt > 16) cnt = 16;
        int j = kc + e4;
        int src = csr[(j < end) ? j : beg];
        float e = als[src * 4 + h4] + aldv;
        e = fmaxf(e, 0.2f * e);
        float myw = __expf(e);
        if (cnt == 16) {
            int sj[16];
#pragma unroll
            for (int jj = 0; jj < 16; ++jj) sj[jj] = __shfl(src, jj * 4);
            if (V == 1) {
                float pv[16];
#pragma unroll
                for (int jj = 0; jj < 16; ++jj) pv[jj] = ld1(&x[(size_t)sj[jj] * K + lane]);
#pragma unroll
                for (int jj = 0; jj < 16; ++jj) {
                    float w0 = __shfl(myw, jj * 4 + 0), w1 = __shfl(myw, jj * 4 + 1);
                    float w2 = __shfl(myw, jj * 4 + 2), w3 = __shfl(myw, jj * 4 + 3);
                    s0 += w0; s1 += w1; s2 += w2; s3 += w3;
                    acc[0][0] += w0 * pv[jj]; acc[1][0] += w1 * pv[jj];
                    acc[2][0] += w2 * pv[jj]; acc[3][0] += w3 * pv[jj];
                }
            } else {
                float2 pv[16];
#pragma unroll
                for (int jj = 0; jj < 16; ++jj) pv[jj] = ld2(&x[(size_t)sj[jj] * K + lane * 2]);
#pragma unroll
                for (int jj = 0; jj < 16; ++jj) {
                    float w0 = __shfl(myw, jj * 4 + 0), w1 = __shfl(myw, jj * 4 + 1);
                    float w2 = __shfl(myw, jj * 4 + 2), w3 = __shfl(myw, jj * 4 + 3);
                    s0 += w0; s1 += w1; s2 += w2; s3 += w3;
                    acc[0][0] += w0 * pv[jj].x; acc[0][1] += w0 * pv[jj].y;
                    acc[1][0] += w1 * pv[jj].x; acc[1][1] += w1 * pv[jj].y;
                    acc[2][0] += w2 * pv[jj].x; acc[2][1] += w2 * pv[jj].y;
                    acc[3][0] += w3 * pv[jj].x; acc[3][1] += w3 * pv[jj].y;
                }
            }
        } else {
            for (int jj = 0; jj < cnt; ++jj) {
                int sjj = __shfl(src, jj * 4);
                float w0 = __shfl(myw, jj * 4 + 0), w1 = __shfl(myw, jj * 4 + 1);
                float w2 = __shfl(myw, jj * 4 + 2), w3 = __shfl(myw, jj * 4 + 3);
                s0 += w0; s1 += w1; s2 += w2; s3 += w3;
                if (V == 1) {
                    float v = ld1(&x[(size_t)sjj * K + lane]);
                    acc[0][0] += w0 * v; acc[1][0] += w1 * v;
                    acc[2][0] += w2 * v; acc[3][0] += w3 * v;
                } else {
                    float2 v = ld2(&x[(size_t)sjj * K + lane * 2]);
                    acc[0][0] += w0 * v.x; acc[0][1] += w0 * v.y;
                    acc[1][0] += w1 * v.x; acc[1][1] += w1 * v.y;
                    acc[2][0] += w2 * v.x; acc[2][1] += w2 * v.y;
                    acc[3][0] += w3 * v.x; acc[3][1] += w3 * v.y;
                }
            }
        }
    }
    float inv[4] = {1.f / (s0 + 1e-16f), 1.f / (s1 + 1e-16f),
                    1.f / (s2 + 1e-16f), 1.f / (s3 + 1e-16f)};
    size_t o = (size_t)wave * 4 * K;
#pragma unroll
    for (int h = 0; h < 4; ++h) {
        if (V == 1) {
            st1(&agg[o + h * K + lane], acc[h][0] * inv[h]);
        } else {
            st2(&agg[o + h * K + lane * 2], acc[h][0] * inv[h], acc[h][1] * inv[h]);
        }
    }
}

// ---------------- fused gather (post-GEMM, L2): head-interleaved h2[N][4*32], bias added ----------------
template <typename TIN, typename TOUT>
__global__ void gather_post32_kernel(const TIN* __restrict__ h2, const float* __restrict__ als,
                                     const float* __restrict__ ald, const int* __restrict__ rowptr,
                                     const int* __restrict__ csr, const float* __restrict__ bias,
                                     TOUT* __restrict__ outp, int N) {
    int wave = (blockIdx.x * blockDim.x + threadIdx.x) >> 6;
    int lane = threadIdx.x & 63;
    if (wave >= N) return;
    int h4 = lane & 3, e4 = lane >> 2;
    int hh = lane >> 4, l16 = lane & 15;
    float aldv = ald[wave * 4 + h4];
    float s = 0.f, a0 = 0.f, a1 = 0.f;
    int beg = rowptr[wave], end = rowptr[wave + 1];
    for (int kc = beg; kc < end; kc += 16) {
        int cnt = end - kc;
        if (cnt > 16) cnt = 16;
        int j = kc + e4;
        int src = csr[(j < end) ? j : beg];
        float e = als[src * 4 + h4] + aldv;
        e = fmaxf(e, 0.2f * e);
        float myw = __expf(e);
        if (cnt == 16) {
            int sj[16];
#pragma unroll
            for (int jj = 0; jj < 16; ++jj) sj[jj] = __shfl(src, jj * 4);
            float2 pv[16];
#pragma unroll
            for (int jj = 0; jj < 16; ++jj)
                pv[jj] = ld2(&h2[(size_t)sj[jj] * 128 + hh * 32 + l16 * 2]);
#pragma unroll
            for (int jj = 0; jj < 16; ++jj) {
                float w = __shfl(myw, jj * 4 + hh);
                s += w;
                a0 += w * pv[jj].x;
                a1 += w * pv[jj].y;
            }
        } else {
            for (int jj = 0; jj < cnt; ++jj) {
                int sjj = __shfl(src, jj * 4);
                float w = __shfl(myw, jj * 4 + hh);
                s += w;
                float2 v = ld2(&h2[(size_t)sjj * 128 + hh * 32 + l16 * 2]);
                a0 += w * v.x;
                a1 += w * v.y;
            }
        }
    }
    float inv = 1.f / (s + 1e-16f);
    int c = hh * 32 + l16 * 2;
    st2(&outp[(size_t)wave * 128 + c], a0 * inv + bias[c], a1 * inv + bias[c + 1]);
}

// ---------------- MFMA GEMM: O[N, col0..+63] = A[N, aOff..+K) @ Bt^T, BM=128 BN=64 BK=32 ----------------
template <typename TOUT>
__global__ __launch_bounds__(256) void mfma_gemm_kernel(
    const __hip_bfloat16* __restrict__ A, int lda, int aSel,
    const __hip_bfloat16* __restrict__ Bt,
    TOUT* __restrict__ O, int ldo,
    const float* __restrict__ bias, int N, int K) {
    __shared__ __hip_bfloat16 As[128][40];
    __shared__ __hip_bfloat16 Bs[64][40];
    int col0 = blockIdx.x * 64;
    int row0 = blockIdx.y * 128;
    int aOff = aSel ? col0 : 0;
    int tid = threadIdx.x;
    int wv = tid >> 6, lane = tid & 63;
    int g = lane >> 4, l16 = lane & 15;
    f32x4 acc[2][4] = {};

    for (int k0 = 0; k0 < K; k0 += 32) {
#pragma unroll
        for (int i = 0; i < 2; ++i) {
            int idx = tid + i * 256;
            int r = idx >> 2, h4 = idx & 3;
            int gr = row0 + r;
            uint4 v = make_uint4(0, 0, 0, 0);
            if (gr < N) v = *reinterpret_cast<const uint4*>(&A[(size_t)gr * lda + aOff + k0 + h4 * 8]);
            *reinterpret_cast<uint4*>(&As[r][h4 * 8]) = v;
        }
        {
            int r = tid >> 2, h4 = tid & 3;
            uint4 v = *reinterpret_cast<const uint4*>(&Bt[(size_t)(col0 + r) * K + k0 + h4 * 8]);
            *reinterpret_cast<uint4*>(&Bs[r][h4 * 8]) = v;
        }
        __syncthreads();
        s16x8 af[2], bf[4];
#pragma unroll
        for (int m = 0; m < 2; ++m)
            af[m] = *reinterpret_cast<const s16x8*>(&As[wv * 32 + m * 16 + l16][g * 8]);
#pragma unroll
        for (int n = 0; n < 4; ++n)
            bf[n] = *reinterpret_cast<const s16x8*>(&Bs[n * 16 + l16][g * 8]);
#pragma unroll
        for (int m = 0; m < 2; ++m)
#pragma unroll
            for (int n = 0; n < 4; ++n)
                acc[m][n] = __builtin_amdgcn_mfma_f32_16x16x32_bf16(af[m], bf[n], acc[m][n], 0, 0, 0);
        __syncthreads();
    }
#pragma unroll
    for (int m = 0; m < 2; ++m) {
#pragma unroll
        for (int rr = 0; rr < 4; ++rr) {
            int row = row0 + wv * 32 + m * 16 + g * 4 + rr;
            if (row < N) {
#pragma unroll
                for (int n = 0; n < 4; ++n) {
                    int col = col0 + n * 16 + l16;
                    float v = acc[m][n][rr];
                    if (bias) v += bias[col];
                    st1(&O[(size_t)row * ldo + col], v);
                }
            }
        }
    }
}

// ---------------- launch ----------------
extern "C" void kernel_launch(void* const* d_in, const int* in_sizes, int n_in,
                              void* d_out, int out_size, void* d_ws, size_t ws_size,
                              hipStream_t stream) {
    const float* x      = (const float*)d_in[0];
    const int*   eidx   = (const int*)d_in[1];
    const float* W1     = (const float*)d_in[2];
    const float* a1_src = (const float*)d_in[3];
    const float* a1_dst = (const float*)d_in[4];
    const float* b1     = (const float*)d_in[5];
    const float* W2     = (const float*)d_in[6];
    const float* a2_src = (const float*)d_in[7];
    const float* a2_dst = (const float*)d_in[8];
    const float* b2     = (const float*)d_in[9];
    const float* W3     = (const float*)d_in[10];
    const float* a3_src = (const float*)d_in[11];
    const float* a3_dst = (const float*)d_in[12];
    const float* b3     = (const float*)d_in[13];
    float* out = (float*)d_out;

    const int N = in_sizes[0] / 64;      // 50000
    const int E = in_sizes[1] / 2;       // 800000
    const int NB = (N + 1023) / 1024;

    // ---- workspace: ints, small floats, Bt weights, then arena F ----
    int* rowptr = (int*)d_ws;
    int* deg    = rowptr + (N + 1);
    int* cursor = deg + N;
    int* csr    = cursor + N;
    int* flag   = csr + E;
    int* bsum   = flag + 1;
    int* boff   = bsum + NB;
    uintptr_t pa = (uintptr_t)(boff + NB);
    pa = (pa + 255) & ~(uintptr_t)255;
    float* als  = (float*)pa;                       // N*4
    float* ald  = als + (size_t)N * 4;              // N*4
    float* ps1  = ald + (size_t)N * 4;              // 256
    float* pd1  = ps1 + 256;                        // 256
    float* ps3  = pd1 + 256;                        // 512
    float* pd3  = ps3 + 512;                        // 512
    __hip_bfloat16* Bt1 = (__hip_bfloat16*)(pd3 + 512);   // 256*64
    __hip_bfloat16* Bt2 = Bt1 + 256 * 64;                 // 128*256
    __hip_bfloat16* Bt3 = Bt2 + 128 * 256;                // 64*512
    uintptr_t pf = (uintptr_t)(Bt3 + 64 * 512);
    pf = (pf + 255) & ~(uintptr_t)255;
    float* F    = (float*)pf;

    // arena (float units): xb 32N | agg1b 128N | out1b 128N | h2b 64N | out2b 64N | agg3 256N = 672N
    __hip_bfloat16* xb    = (__hip_bfloat16*)F;
    __hip_bfloat16* agg1b = (__hip_bfloat16*)(F + (size_t)N * 32);
    __hip_bfloat16* out1b = (__hip_bfloat16*)(F + (size_t)N * 160);
    __hip_bfloat16* h2b   = (__hip_bfloat16*)(F + (size_t)N * 288);
    __hip_bfloat16* out2b = (__hip_bfloat16*)(F + (size_t)N * 352);
    __hip_bfloat16* agg3  = (__hip_bfloat16*)(F + (size_t)N * 416);

    // ---- CSR build (7 dispatches) ----
    detect_kernel<<<1, 64, 0, stream>>>(eidx, flag);
    hipMemsetAsync(deg, 0, (size_t)N * sizeof(int), stream);
    deg_kernel<<<(E + 255) / 256, 256, 0, stream>>>(eidx, flag, deg, E, N);
    reduce_kernel<<<NB, 256, 0, stream>>>(deg, bsum, N);
    scan_bsum_kernel<<<1, 64, 0, stream>>>(bsum, boff, NB, rowptr + N);
    block_scan_kernel<<<NB, 256, 0, stream>>>(deg, boff, rowptr, cursor, N);
    scatter_kernel<<<(E + 255) / 256, 256, 0, stream>>>(eidx, flag, cursor, csr, E, N);

    // ---- fused prep (1 dispatch) ----
    const int n8 = N * 8;
    const int nXB = (n8 + 255) / 256;
    prep_kernel<<<nXB + 64 + 128 + 128 + 1 + 2, 256, 0, stream>>>(
        x, W1, W2, W3, a1_src, a1_dst, a3_src, a3_dst,
        xb, Bt1, Bt2, Bt3, ps1, pd1, ps3, pd3, n8);

    const int alBlocks  = (N * HEADS + 255) / 256;
    const int aggBlocks = (N + 3) / 4;
    const int rowB128   = (N + 127) / 128;

    // ---- layer 1: pre-agg x (fused weights), per-head MFMA GEMM ----
    alx_kernel<64, float><<<alBlocks, 256, 0, stream>>>(x, ps1, pd1, als, ald, N);
    gather_pre_kernel<64, __hip_bfloat16, __hip_bfloat16><<<aggBlocks, 256, 0, stream>>>(
        xb, als, ald, rowptr, csr, agg1b, N);
    mfma_gemm_kernel<__hip_bfloat16><<<dim3(4, rowB128), 256, 0, stream>>>(
        agg1b, 256, 1, Bt1, out1b, 256, b1, N, 64);

    // ---- layer 2: GEMM then post-agg (fused weights) ----
    mfma_gemm_kernel<__hip_bfloat16><<<dim3(2, rowB128), 256, 0, stream>>>(
        out1b, 256, 0, Bt2, h2b, 128, nullptr, N, 256);
    al_kernel<32, __hip_bfloat16><<<alBlocks, 256, 0, stream>>>(h2b, a2_src, a2_dst, als, ald, N);
    gather_post32_kernel<__hip_bfloat16, __hip_bfloat16><<<aggBlocks, 256, 0, stream>>>(
        h2b, als, ald, rowptr, csr, b2, out2b, N);

    // ---- layer 3: pre-agg out2 (fused weights), stacked GEMM with mean folded ----
    alx_kernel<128, __hip_bfloat16><<<alBlocks, 256, 0, stream>>>(out2b, ps3, pd3, als, ald, N);
    gather_pre_kernel<128, __hip_bfloat16, __hip_bfloat16><<<aggBlocks, 256, 0, stream>>>(
        out2b, als, ald, rowptr, csr, agg3, N);
    mfma_gemm_kernel<float><<<dim3(1, rowB128), 256, 0, stream>>>(
        agg3, 512, 0, Bt3, out, 64, b3, N, 512);
}

// Round 11
// 353.765 us; speedup vs baseline: 2.3649x; 1.1162x over previous
//
#include <hip/hip_runtime.h>
#include <hip/hip_bf16.h>

#define HEADS 4

typedef __attribute__((ext_vector_type(4))) float f32x4;
typedef __attribute__((ext_vector_type(8))) short s16x8;

// ---------------- bf16 helpers ----------------
__device__ __forceinline__ float u2f(unsigned short u) {
    return __uint_as_float(((unsigned)u) << 16);
}
__device__ __forceinline__ unsigned short rne(float v) {
    unsigned b = __float_as_uint(v);
    return (unsigned short)((b + 0x7FFF + ((b >> 16) & 1)) >> 16);
}
__device__ __forceinline__ float ld1(const float* p) { return *p; }
__device__ __forceinline__ float ld1(const __hip_bfloat16* p) {
    return u2f(*reinterpret_cast<const unsigned short*>(p));
}
__device__ __forceinline__ float2 ld2(const float* p) { return *reinterpret_cast<const float2*>(p); }
__device__ __forceinline__ float2 ld2(const __hip_bfloat16* p) {
    ushort2 u = *reinterpret_cast<const ushort2*>(p);
    return make_float2(u2f(u.x), u2f(u.y));
}
__device__ __forceinline__ float4 ld4(const float* p) { return *reinterpret_cast<const float4*>(p); }
__device__ __forceinline__ float4 ld4(const __hip_bfloat16* p) {
    ushort4 u = *reinterpret_cast<const ushort4*>(p);
    return make_float4(u2f(u.x), u2f(u.y), u2f(u.z), u2f(u.w));
}
__device__ __forceinline__ void st1(float* p, float v) { *p = v; }
__device__ __forceinline__ void st1(__hip_bfloat16* p, float v) {
    *reinterpret_cast<unsigned short*>(p) = rne(v);
}
__device__ __forceinline__ void st2(float* p, float a, float b) {
    *reinterpret_cast<float2*>(p) = make_float2(a, b);
}
__device__ __forceinline__ void st2(__hip_bfloat16* p, float a, float b) {
    *reinterpret_cast<ushort2*>(p) = make_ushort2(rne(a), rne(b));
}
__device__ __forceinline__ void st4(float* p, float4 v) { *reinterpret_cast<float4*>(p) = v; }
__device__ __forceinline__ void st4(__hip_bfloat16* p, float4 v) {
    *reinterpret_cast<ushort4*>(p) = make_ushort4(rne(v.x), rne(v.y), rne(v.z), rne(v.w));
}

// ---------------- inline int64-layout detection ----------------
// int64 edge_index: every odd 32-bit word (high half) is 0. Check 4 fixed words
// (wave-uniform -> scalar loads). False positive prob ~ (1/N)^4 ~ 0.
__device__ __forceinline__ int detect64(const int* __restrict__ e) {
    return ((e[1] | e[3] | e[5] | e[7]) == 0) ? 1 : 0;
}
__device__ __forceinline__ int edge_elem(const int* e, size_t idx, int is64) {
    return is64 ? e[2 * idx] : e[idx];
}

// ---------------- CSR build ----------------
__global__ void deg_kernel(const int* __restrict__ eidx, int* __restrict__ deg, int E, int N) {
    int e = blockIdx.x * blockDim.x + threadIdx.x;
    if (e < E) {
        int is64 = detect64(eidx);
        int d = edge_elem(eidx, (size_t)E + e, is64);
        if ((unsigned)d < (unsigned)N) atomicAdd(&deg[d], 1);
    }
}

__global__ void reduce_kernel(const int* __restrict__ deg, int* __restrict__ bsum, int n) {
    __shared__ int sdata[256];
    int base = blockIdx.x * 1024;
    int t = threadIdx.x;
    int v = 0;
#pragma unroll
    for (int j = 0; j < 4; ++j) {
        int i = base + t + j * 256;
        if (i < n) v += deg[i];
    }
    sdata[t] = v;
    __syncthreads();
    for (int off = 128; off > 0; off >>= 1) {
        if (t < off) sdata[t] += sdata[t + off];
        __syncthreads();
    }
    if (t == 0) bsum[blockIdx.x] = sdata[0];
}

__global__ void scan_bsum_kernel(const int* __restrict__ bsum, int* __restrict__ boff,
                                 int nb, int* __restrict__ totalp) {
    int lane = threadIdx.x;
    int carry = 0;
    for (int base = 0; base < nb; base += 64) {
        int i = base + lane;
        int v = (i < nb) ? bsum[i] : 0;
        int inc = v;
        for (int off = 1; off < 64; off <<= 1) {
            int tt = __shfl_up(inc, off);
            if (lane >= off) inc += tt;
        }
        if (i < nb) boff[i] = carry + inc - v;
        carry += __shfl(inc, 63);
    }
    if (lane == 0) *totalp = carry;
}

__global__ void block_scan_kernel(const int* __restrict__ deg, const int* __restrict__ boff,
                                  int* __restrict__ rowptr, int* __restrict__ cursor, int n) {
    __shared__ int wsum[4];
    int base = blockIdx.x * 1024;
    int t = threadIdx.x;
    int lane = t & 63, w = t >> 6;
    int v[4];
    int lsum = 0;
#pragma unroll
    for (int j = 0; j < 4; ++j) {
        int i = base + t * 4 + j;
        v[j] = (i < n) ? deg[i] : 0;
        lsum += v[j];
    }
    int inc = lsum;
    for (int off = 1; off < 64; off <<= 1) {
        int tt = __shfl_up(inc, off);
        if (lane >= off) inc += tt;
    }
    if (lane == 63) wsum[w] = inc;
    __syncthreads();
    int woff = 0;
    for (int i = 0; i < w; ++i) woff += wsum[i];
    int ex = boff[blockIdx.x] + woff + inc - lsum;
#pragma unroll
    for (int j = 0; j < 4; ++j) {
        int i = base + t * 4 + j;
        if (i < n) { rowptr[i] = ex; cursor[i] = ex; }
        ex += v[j];
    }
}

__global__ void scatter_kernel(const int* __restrict__ eidx, int* __restrict__ cursor,
                               int* __restrict__ csr_src, int E, int N) {
    int e = blockIdx.x * blockDim.x + threadIdx.x;
    if (e < E) {
        int is64 = detect64(eidx);
        int s = edge_elem(eidx, (size_t)e, is64);
        int d = edge_elem(eidx, (size_t)E + e, is64);
        if ((unsigned)d < (unsigned)N && (unsigned)s < (unsigned)N) {
            int pos = atomicAdd(&cursor[d], 1);
            csr_src[pos] = s;
        }
    }
}

// ---------------- fused prep: xb, Bt3, Wcat (BtF), bias12, proj1, proj3 ----------------
// BtF[m][k] (bf16, 128x256) = sum_c W1[k&63, (k>>6)*64+c] * W2[(k>>6)*64+c, m]  (gemm1+gemm2 folded)
// bias12[m] = sum_j b1[j] * W2[j, m]
__global__ void prep_kernel(const float* __restrict__ x,
                            const float* __restrict__ W1, const float* __restrict__ W2,
                            const float* __restrict__ W3, const float* __restrict__ b1,
                            const float* __restrict__ a1s, const float* __restrict__ a1d,
                            const float* __restrict__ a3s, const float* __restrict__ a3d,
                            __hip_bfloat16* __restrict__ xb,
                            __hip_bfloat16* __restrict__ Bt3, __hip_bfloat16* __restrict__ BtF,
                            float* __restrict__ bias12,
                            float* __restrict__ ps1, float* __restrict__ pd1,
                            float* __restrict__ ps3, float* __restrict__ pd3, int n8) {
    int b = blockIdx.x, t = threadIdx.x;
    int nXB = (n8 + 255) / 256;
    if (b < nXB) {
        int i = b * 256 + t;
        if (i < n8) {
            float4 a = *reinterpret_cast<const float4*>(&x[(size_t)i * 8]);
            float4 c = *reinterpret_cast<const float4*>(&x[(size_t)i * 8 + 4]);
            st4(&xb[(size_t)i * 8], a);
            st4(&xb[(size_t)i * 8 + 4], c);
        }
        return;
    }
    b -= nXB;
    if (b < 128) {  // Bt3 [64][512]: Bt3[c*512 + h*128+kk] = W3[kk*256 + h*64 + c] * 0.25
        int idx = b * 256 + t;
        int c = idx >> 9, r = idx & 511;
        int h = r >> 7, kk = r & 127;
        st1(&Bt3[idx], W3[(size_t)kk * 256 + h * 64 + c] * 0.25f);
        return;
    }
    b -= 128;
    if (b < 128) {  // BtF [128][256]
        int idx = b * 256 + t;
        int m = idx >> 8, k = idx & 255;
        int h = k >> 6, kin = k & 63;
        float acc = 0.f;
        for (int c = 0; c < 64; ++c)
            acc += W1[(size_t)kin * 256 + h * 64 + c] * W2[(size_t)(h * 64 + c) * 128 + m];
        st1(&BtF[idx], acc);
        return;
    }
    b -= 128;
    if (b < 1) {  // bias12
        if (t < 128) {
            float acc = 0.f;
            for (int j = 0; j < 256; ++j) acc += b1[j] * W2[(size_t)j * 128 + t];
            bias12[t] = acc;
        }
        return;
    }
    b -= 1;
    if (b < 1) {  // proj1: ps1[h*64+k]
        int h = t >> 6, k = t & 63;
        float ss = 0.f, sd = 0.f;
        for (int c = 0; c < 64; ++c) {
            float w = W1[(size_t)k * 256 + h * 64 + c];
            ss += w * a1s[h * 64 + c];
            sd += w * a1d[h * 64 + c];
        }
        ps1[t] = ss;
        pd1[t] = sd;
        return;
    }
    b -= 1;
    if (b < 2) {  // proj3: ps3[h*128+k]
        int idx = b * 256 + t;
        int h = idx >> 7, k = idx & 127;
        float ss = 0.f, sd = 0.f;
        for (int c = 0; c < 64; ++c) {
            float w = W3[(size_t)k * 256 + h * 64 + c];
            ss += w * a3s[h * 64 + c];
            sd += w * a3d[h * 64 + c];
        }
        ps3[idx] = ss;
        pd3[idx] = sd;
        return;
    }
}

// ---------------- logits from raw features (L1) ----------------
template <int K, typename T>
__global__ void alx_kernel(const T* __restrict__ x, const float* __restrict__ ps,
                           const float* __restrict__ pd, float* __restrict__ als,
                           float* __restrict__ ald, int N) {
    int idx = blockIdx.x * blockDim.x + threadIdx.x;
    if (idx >= N * 4) return;
    int n = idx >> 2, h = idx & 3;
    const T* row = x + (size_t)n * K;
    const float* vs = ps + h * K;
    const float* vd = pd + h * K;
    float ss = 0.f, sd = 0.f;
#pragma unroll
    for (int c = 0; c < K; c += 4) {
        float4 v = ld4(&row[c]);
        float4 a = *reinterpret_cast<const float4*>(&vs[c]);
        float4 b = *reinterpret_cast<const float4*>(&vd[c]);
        ss += v.x * a.x + v.y * a.y + v.z * a.z + v.w * a.w;
        sd += v.x * b.x + v.y * b.y + v.z * b.z + v.w * b.w;
    }
    als[idx] = ss;
    ald[idx] = sd;
}

// ---------------- logits from interleaved head features (L2) ----------------
template <int C, typename T>
__global__ void al_kernel(const T* __restrict__ h,
                          const float* __restrict__ a_src, const float* __restrict__ a_dst,
                          float* __restrict__ al_s, float* __restrict__ al_d, int N) {
    int idx = blockIdx.x * blockDim.x + threadIdx.x;
    if (idx >= N * HEADS) return;
    int n = idx >> 2, hd = idx & 3;
    const T* row = h + (size_t)n * HEADS * C + hd * C;
    float ss = 0.f, sd = 0.f;
#pragma unroll
    for (int c = 0; c < C; c += 4) {
        float4 v = ld4(&row[c]);
        float4 as = *reinterpret_cast<const float4*>(&a_src[hd * C + c]);
        float4 ad = *reinterpret_cast<const float4*>(&a_dst[hd * C + c]);
        ss += v.x * as.x + v.y * as.y + v.z * as.z + v.w * as.w;
        sd += v.x * ad.x + v.y * ad.y + v.z * ad.z + v.w * ad.w;
    }
    al_s[idx] = ss;
    al_d[idx] = sd;
}

// ---------------- fused gather (pre-agg), wave-internal weight production ----------------
template <int K, typename TIN, typename TOUT>
__global__ void gather_pre_kernel(const TIN* __restrict__ x, const float* __restrict__ als,
                                  const float* __restrict__ ald, const int* __restrict__ rowptr,
                                  const int* __restrict__ csr, TOUT* __restrict__ agg, int N) {
    constexpr int V = K / 64;  // 1 (K=64) or 2 (K=128)
    int wave = (blockIdx.x * blockDim.x + threadIdx.x) >> 6;
    int lane = threadIdx.x & 63;
    if (wave >= N) return;
    int h4 = lane & 3, e4 = lane >> 2;
    float aldv = ald[wave * 4 + h4];
    float s0 = 0.f, s1 = 0.f, s2 = 0.f, s3 = 0.f;
    float acc[4][V] = {};
    int beg = rowptr[wave], end = rowptr[wave + 1];
    for (int kc = beg; kc < end; kc += 16) {
        int cnt = end - kc;
        if (cnt > 16) cnt = 16;
        int j = kc + e4;
        int src = csr[(j < end) ? j : beg];
        float e = als[src * 4 + h4] + aldv;
        e = fmaxf(e, 0.2f * e);
        float myw = __expf(e);
        if (cnt == 16) {
            int sj[16];
#pragma unroll
            for (int jj = 0; jj < 16; ++jj) sj[jj] = __shfl(src, jj * 4);
            if (V == 1) {
                float pv[16];
#pragma unroll
                for (int jj = 0; jj < 16; ++jj) pv[jj] = ld1(&x[(size_t)sj[jj] * K + lane]);
#pragma unroll
                for (int jj = 0; jj < 16; ++jj) {
                    float w0 = __shfl(myw, jj * 4 + 0), w1 = __shfl(myw, jj * 4 + 1);
                    float w2 = __shfl(myw, jj * 4 + 2), w3 = __shfl(myw, jj * 4 + 3);
                    s0 += w0; s1 += w1; s2 += w2; s3 += w3;
                    acc[0][0] += w0 * pv[jj]; acc[1][0] += w1 * pv[jj];
                    acc[2][0] += w2 * pv[jj]; acc[3][0] += w3 * pv[jj];
                }
            } else {
                float2 pv[16];
#pragma unroll
                for (int jj = 0; jj < 16; ++jj) pv[jj] = ld2(&x[(size_t)sj[jj] * K + lane * 2]);
#pragma unroll
                for (int jj = 0; jj < 16; ++jj) {
                    float w0 = __shfl(myw, jj * 4 + 0), w1 = __shfl(myw, jj * 4 + 1);
                    float w2 = __shfl(myw, jj * 4 + 2), w3 = __shfl(myw, jj * 4 + 3);
                    s0 += w0; s1 += w1; s2 += w2; s3 += w3;
                    acc[0][0] += w0 * pv[jj].x; acc[0][1] += w0 * pv[jj].y;
                    acc[1][0] += w1 * pv[jj].x; acc[1][1] += w1 * pv[jj].y;
                    acc[2][0] += w2 * pv[jj].x; acc[2][1] += w2 * pv[jj].y;
                    acc[3][0] += w3 * pv[jj].x; acc[3][1] += w3 * pv[jj].y;
                }
            }
        } else {
            for (int jj = 0; jj < cnt; ++jj) {
                int sjj = __shfl(src, jj * 4);
                float w0 = __shfl(myw, jj * 4 + 0), w1 = __shfl(myw, jj * 4 + 1);
                float w2 = __shfl(myw, jj * 4 + 2), w3 = __shfl(myw, jj * 4 + 3);
                s0 += w0; s1 += w1; s2 += w2; s3 += w3;
                if (V == 1) {
                    float v = ld1(&x[(size_t)sjj * K + lane]);
                    acc[0][0] += w0 * v; acc[1][0] += w1 * v;
                    acc[2][0] += w2 * v; acc[3][0] += w3 * v;
                } else {
                    float2 v = ld2(&x[(size_t)sjj * K + lane * 2]);
                    acc[0][0] += w0 * v.x; acc[0][1] += w0 * v.y;
                    acc[1][0] += w1 * v.x; acc[1][1] += w1 * v.y;
                    acc[2][0] += w2 * v.x; acc[2][1] += w2 * v.y;
                    acc[3][0] += w3 * v.x; acc[3][1] += w3 * v.y;
                }
            }
        }
    }
    float inv[4] = {1.f / (s0 + 1e-16f), 1.f / (s1 + 1e-16f),
                    1.f / (s2 + 1e-16f), 1.f / (s3 + 1e-16f)};
    size_t o = (size_t)wave * 4 * K;
#pragma unroll
    for (int h = 0; h < 4; ++h) {
        if (V == 1) {
            st1(&agg[o + h * K + lane], acc[h][0] * inv[h]);
        } else {
            st2(&agg[o + h * K + lane * 2], acc[h][0] * inv[h], acc[h][1] * inv[h]);
        }
    }
}

// ---------------- fused gather (post-GEMM L2) + layer-3 logits epilogue ----------------
// Each wave produces its node's full 128-ch out2 row -> compute als3/ald3 in-register.
template <typename TIN, typename TOUT>
__global__ void gather_post32_alx_kernel(const TIN* __restrict__ h2, const float* __restrict__ als,
                                         const float* __restrict__ ald, const int* __restrict__ rowptr,
                                         const int* __restrict__ csr, const float* __restrict__ bias,
                                         const float* __restrict__ ps3, const float* __restrict__ pd3,
                                         TOUT* __restrict__ outp,
                                         float* __restrict__ als3, float* __restrict__ ald3, int N) {
    int wave = (blockIdx.x * blockDim.x + threadIdx.x) >> 6;
    int lane = threadIdx.x & 63;
    if (wave >= N) return;
    int h4 = lane & 3, e4 = lane >> 2;
    int hh = lane >> 4, l16 = lane & 15;
    float aldv = ald[wave * 4 + h4];
    float s = 0.f, a0 = 0.f, a1 = 0.f;
    int beg = rowptr[wave], end = rowptr[wave + 1];
    for (int kc = beg; kc < end; kc += 16) {
        int cnt = end - kc;
        if (cnt > 16) cnt = 16;
        int j = kc + e4;
        int src = csr[(j < end) ? j : beg];
        float e = als[src * 4 + h4] + aldv;
        e = fmaxf(e, 0.2f * e);
        float myw = __expf(e);
        if (cnt == 16) {
            int sj[16];
#pragma unroll
            for (int jj = 0; jj < 16; ++jj) sj[jj] = __shfl(src, jj * 4);
            float2 pv[16];
#pragma unroll
            for (int jj = 0; jj < 16; ++jj)
                pv[jj] = ld2(&h2[(size_t)sj[jj] * 128 + hh * 32 + l16 * 2]);
#pragma unroll
            for (int jj = 0; jj < 16; ++jj) {
                float w = __shfl(myw, jj * 4 + hh);
                s += w;
                a0 += w * pv[jj].x;
                a1 += w * pv[jj].y;
            }
        } else {
            for (int jj = 0; jj < cnt; ++jj) {
                int sjj = __shfl(src, jj * 4);
                float w = __shfl(myw, jj * 4 + hh);
                s += w;
                float2 v = ld2(&h2[(size_t)sjj * 128 + hh * 32 + l16 * 2]);
                a0 += w * v.x;
                a1 += w * v.y;
            }
        }
    }
    float inv = 1.f / (s + 1e-16f);
    int c = hh * 32 + l16 * 2;
    float v0 = a0 * inv + bias[c];
    float v1 = a1 * inv + bias[c + 1];
    st2(&outp[(size_t)wave * 128 + c], v0, v1);

    // ---- layer-3 logits: als3[n,h] = out2[n,:] . ps3[h,:] ----
    float sArr[4], dArr[4];
#pragma unroll
    for (int h = 0; h < 4; ++h) {
        float2 vs = *reinterpret_cast<const float2*>(&ps3[h * 128 + c]);
        float2 vd = *reinterpret_cast<const float2*>(&pd3[h * 128 + c]);
        sArr[h] = v0 * vs.x + v1 * vs.y;
        dArr[h] = v0 * vd.x + v1 * vd.y;
    }
#pragma unroll
    for (int off = 1; off < 64; off <<= 1) {
#pragma unroll
        for (int h = 0; h < 4; ++h) {
            sArr[h] += __shfl_xor(sArr[h], off);
            dArr[h] += __shfl_xor(dArr[h], off);
        }
    }
    if (lane < 4) {
        float os = (lane == 0) ? sArr[0] : (lane == 1) ? sArr[1] : (lane == 2) ? sArr[2] : sArr[3];
        float od = (lane == 0) ? dArr[0] : (lane == 1) ? dArr[1] : (lane == 2) ? dArr[2] : dArr[3];
        als3[wave * 4 + lane] = os;
        ald3[wave * 4 + lane] = od;
    }
}

// ---------------- MFMA GEMM: O[N, col0..+63] = A[N, aOff..+K) @ Bt^T, BM=128 BN=64 BK=32 ----------------
template <typename TOUT>
__global__ __launch_bounds__(256) void mfma_gemm_kernel(
    const __hip_bfloat16* __restrict__ A, int lda, int aSel,
    const __hip_bfloat16* __restrict__ Bt,
    TOUT* __restrict__ O, int ldo,
    const float* __restrict__ bias, int N, int K) {
    __shared__ __hip_bfloat16 As[128][40];
    __shared__ __hip_bfloat16 Bs[64][40];
    int col0 = blockIdx.x * 64;
    int row0 = blockIdx.y * 128;
    int aOff = aSel ? col0 : 0;
    int tid = threadIdx.x;
    int wv = tid >> 6, lane = tid & 63;
    int g = lane >> 4, l16 = lane & 15;
    f32x4 acc[2][4] = {};

    for (int k0 = 0; k0 < K; k0 += 32) {
#pragma unroll
        for (int i = 0; i < 2; ++i) {
            int idx = tid + i * 256;
            int r = idx >> 2, h4 = idx & 3;
            int gr = row0 + r;
            uint4 v = make_uint4(0, 0, 0, 0);
            if (gr < N) v = *reinterpret_cast<const uint4*>(&A[(size_t)gr * lda + aOff + k0 + h4 * 8]);
            *reinterpret_cast<uint4*>(&As[r][h4 * 8]) = v;
        }
        {
            int r = tid >> 2, h4 = tid & 3;
            uint4 v = *reinterpret_cast<const uint4*>(&Bt[(size_t)(col0 + r) * K + k0 + h4 * 8]);
            *reinterpret_cast<uint4*>(&Bs[r][h4 * 8]) = v;
        }
        __syncthreads();
        s16x8 af[2], bf[4];
#pragma unroll
        for (int m = 0; m < 2; ++m)
            af[m] = *reinterpret_cast<const s16x8*>(&As[wv * 32 + m * 16 + l16][g * 8]);
#pragma unroll
        for (int n = 0; n < 4; ++n)
            bf[n] = *reinterpret_cast<const s16x8*>(&Bs[n * 16 + l16][g * 8]);
#pragma unroll
        for (int m = 0; m < 2; ++m)
#pragma unroll
            for (int n = 0; n < 4; ++n)
                acc[m][n] = __builtin_amdgcn_mfma_f32_16x16x32_bf16(af[m], bf[n], acc[m][n], 0, 0, 0);
        __syncthreads();
    }
#pragma unroll
    for (int m = 0; m < 2; ++m) {
#pragma unroll
        for (int rr = 0; rr < 4; ++rr) {
            int row = row0 + wv * 32 + m * 16 + g * 4 + rr;
            if (row < N) {
#pragma unroll
                for (int n = 0; n < 4; ++n) {
                    int col = col0 + n * 16 + l16;
                    float v = acc[m][n][rr];
                    if (bias) v += bias[col];
                    st1(&O[(size_t)row * ldo + col], v);
                }
            }
        }
    }
}

// ---------------- launch ----------------
extern "C" void kernel_launch(void* const* d_in, const int* in_sizes, int n_in,
                              void* d_out, int out_size, void* d_ws, size_t ws_size,
                              hipStream_t stream) {
    const float* x      = (const float*)d_in[0];
    const int*   eidx   = (const int*)d_in[1];
    const float* W1     = (const float*)d_in[2];
    const float* a1_src = (const float*)d_in[3];
    const float* a1_dst = (const float*)d_in[4];
    const float* b1     = (const float*)d_in[5];
    const float* W2     = (const float*)d_in[6];
    const float* a2_src = (const float*)d_in[7];
    const float* a2_dst = (const float*)d_in[8];
    const float* b2     = (const float*)d_in[9];
    const float* W3     = (const float*)d_in[10];
    const float* a3_src = (const float*)d_in[11];
    const float* a3_dst = (const float*)d_in[12];
    const float* b3     = (const float*)d_in[13];
    float* out = (float*)d_out;

    const int N = in_sizes[0] / 64;      // 50000
    const int E = in_sizes[1] / 2;       // 800000
    const int NB = (N + 1023) / 1024;

    // ---- workspace ----
    int* rowptr = (int*)d_ws;
    int* deg    = rowptr + (N + 1);
    int* cursor = deg + N;
    int* csr    = cursor + N;
    int* bsum   = csr + E;
    int* boff   = bsum + NB;
    uintptr_t pa = (uintptr_t)(boff + NB);
    pa = (pa + 255) & ~(uintptr_t)255;
    float* als  = (float*)pa;                       // N*4
    float* ald  = als + (size_t)N * 4;              // N*4
    float* als3 = ald + (size_t)N * 4;              // N*4
    float* ald3 = als3 + (size_t)N * 4;             // N*4
    float* ps1  = ald3 + (size_t)N * 4;             // 256
    float* pd1  = ps1 + 256;                        // 256
    float* ps3  = pd1 + 256;                        // 512
    float* pd3  = ps3 + 512;                        // 512
    float* bias12 = pd3 + 512;                      // 128
    __hip_bfloat16* Bt3 = (__hip_bfloat16*)(bias12 + 128);  // 64*512
    __hip_bfloat16* BtF = Bt3 + 64 * 512;                   // 128*256
    uintptr_t pf = (uintptr_t)(BtF + 128 * 256);
    pf = (pf + 255) & ~(uintptr_t)255;
    float* F    = (float*)pf;

    // arena (float units): xb 32N | agg1b 128N | h2b 64N | out2b 64N | agg3 256N = 544N
    __hip_bfloat16* xb    = (__hip_bfloat16*)F;
    __hip_bfloat16* agg1b = (__hip_bfloat16*)(F + (size_t)N * 32);
    __hip_bfloat16* h2b   = (__hip_bfloat16*)(F + (size_t)N * 160);
    __hip_bfloat16* out2b = (__hip_bfloat16*)(F + (size_t)N * 224);
    __hip_bfloat16* agg3  = (__hip_bfloat16*)(F + (size_t)N * 288);

    // ---- CSR build (6 dispatches) ----
    hipMemsetAsync(deg, 0, (size_t)N * sizeof(int), stream);
    deg_kernel<<<(E + 255) / 256, 256, 0, stream>>>(eidx, deg, E, N);
    reduce_kernel<<<NB, 256, 0, stream>>>(deg, bsum, N);
    scan_bsum_kernel<<<1, 64, 0, stream>>>(bsum, boff, NB, rowptr + N);
    block_scan_kernel<<<NB, 256, 0, stream>>>(deg, boff, rowptr, cursor, N);
    scatter_kernel<<<(E + 255) / 256, 256, 0, stream>>>(eidx, cursor, csr, E, N);

    // ---- fused prep (1 dispatch) ----
    const int n8 = N * 8;
    const int nXB = (n8 + 255) / 256;
    prep_kernel<<<nXB + 128 + 128 + 1 + 1 + 2, 256, 0, stream>>>(
        x, W1, W2, W3, b1, a1_src, a1_dst, a3_src, a3_dst,
        xb, Bt3, BtF, bias12, ps1, pd1, ps3, pd3, n8);

    const int alBlocks  = (N * HEADS + 255) / 256;
    const int aggBlocks = (N + 3) / 4;
    const int rowB128   = (N + 127) / 128;

    // ---- layer 1 gather + fused L1L2-GEMM (agg1 @ Wcat -> h2) ----
    alx_kernel<64, float><<<alBlocks, 256, 0, stream>>>(x, ps1, pd1, als, ald, N);
    gather_pre_kernel<64, __hip_bfloat16, __hip_bfloat16><<<aggBlocks, 256, 0, stream>>>(
        xb, als, ald, rowptr, csr, agg1b, N);
    mfma_gemm_kernel<__hip_bfloat16><<<dim3(2, rowB128), 256, 0, stream>>>(
        agg1b, 256, 0, BtF, h2b, 128, bias12, N, 256);

    // ---- layer 2: logits + gather (with fused layer-3 logits epilogue) ----
    al_kernel<32, __hip_bfloat16><<<alBlocks, 256, 0, stream>>>(h2b, a2_src, a2_dst, als, ald, N);
    gather_post32_alx_kernel<__hip_bfloat16, __hip_bfloat16><<<aggBlocks, 256, 0, stream>>>(
        h2b, als, ald, rowptr, csr, b2, ps3, pd3, out2b, als3, ald3, N);

    // ---- layer 3: gather + stacked GEMM with mean folded ----
    gather_pre_kernel<128, __hip_bfloat16, __hip_bfloat16><<<aggBlocks, 256, 0, stream>>>(
        out2b, als3, ald3, rowptr, csr, agg3, N);
    mfma_gemm_kernel<float><<<dim3(1, rowB128), 256, 0, stream>>>(
        agg3, 512, 0, Bt3, out, 64, b3, N, 512);
}